// Round 10
// baseline (1042.449 us; speedup 1.0000x reference)
//
#include <hip/hip_runtime.h>
#include <cstdint>
#include <cstddef>

typedef unsigned short u16;
typedef unsigned int u32;
typedef __attribute__((ext_vector_type(8))) short bf16x8s;
typedef __attribute__((ext_vector_type(4))) float f32x4;
typedef __attribute__((ext_vector_type(16))) float f32x16;

#define ASG __attribute__((address_space(1)))
#define ASL __attribute__((address_space(3)))

__device__ __forceinline__ u16 f2bf(float f){
  union { float f; unsigned u; } v; v.f = f;
  unsigned r = v.u + 0x7FFFu + ((v.u >> 16) & 1u);
  return (u16)(r >> 16);
}
__device__ __forceinline__ float bf2f(u16 h){
  union { unsigned u; float f; } v; v.u = ((unsigned)h) << 16;
  return v.f;
}

// ---------------- fp32 -> bf16 convert ----------------
__global__ __launch_bounds__(256) void cvt_kernel(const float* __restrict__ in,
                                                  u16* __restrict__ out, int n){
  int i = blockIdx.x*256 + threadIdx.x;
  if (i < n) out[i] = f2bf(in[i]);
}

// ---------------- Wg/Wu -> bf16 interleaved in 32-row blocks: out rows [6144][1152] ----------------
__global__ __launch_bounds__(256) void cvt_gu_kernel(const float* __restrict__ Wg,
                                                     const float* __restrict__ Wu,
                                                     u16* __restrict__ out){
  size_t i = (size_t)blockIdx.x*256 + threadIdx.x;   // over 6144*1152
  if (i >= (size_t)6144*1152) return;
  int j = (int)(i / 1152), k = (int)(i % 1152);
  int b32 = j >> 5, w = j & 31;
  int src = (b32 >> 1)*32 + w;
  const float* W = (b32 & 1) ? Wu : Wg;
  out[i] = f2bf(W[(size_t)src*1152 + k]);
}

// ---------------- temb branch: one wave per col, coalesced Wt reads ----------------
__global__ __launch_bounds__(256) void temb_kernel(const float* __restrict__ temb,
                                                   const float* __restrict__ Wt,
                                                   const float* __restrict__ bt,
                                                   const float* __restrict__ bqkv,
                                                   float* __restrict__ tvec){
  const int col  = blockIdx.x*4 + (threadIdx.x>>6);   // 864 blocks x 4 waves = 3456 cols
  const int lane = threadIdx.x & 63;
  const float* wp = Wt + (size_t)col*1152;
  float w[18];
  #pragma unroll
  for (int j=0;j<18;j++) w[j] = wp[lane + j*64];
  float acc[16];
  #pragma unroll
  for (int b=0;b<16;b++) acc[b] = 0.f;
  #pragma unroll
  for (int j=0;j<18;j++){
    const int k = lane + j*64;
    #pragma unroll
    for (int b=0;b<16;b++) acc[b] += w[j]*temb[b*1152 + k];
  }
  #pragma unroll
  for (int b=0;b<16;b++){
    #pragma unroll
    for (int d=1; d<64; d<<=1) acc[b] += __shfl_xor(acc[b], d);
  }
  if (lane == 0){
    float add = bt[col] + bqkv[col];
    #pragma unroll
    for (int b=0;b<16;b++) tvec[(size_t)b*3456 + col] = acc[b] + add;
  }
}

// ---------------- row RMSNorm (no affine), fp32 in -> bf16 out ----------------
__global__ __launch_bounds__(256) void rms_kernel(const float* __restrict__ in,
                                                  u16* __restrict__ out, int C){
  int row = blockIdx.x;
  const float* p = in + (size_t)row*C;
  float ss = 0.f;
  for (int c = threadIdx.x; c < C; c += 256){ float v = p[c]; ss += v*v; }
  #pragma unroll
  for (int d=1; d<64; d<<=1) ss += __shfl_xor(ss, d);
  __shared__ float wsum[4];
  if ((threadIdx.x & 63) == 0) wsum[threadIdx.x>>6] = ss;
  __syncthreads();
  float tot = wsum[0]+wsum[1]+wsum[2]+wsum[3];
  float r = rsqrtf(tot/(float)C + 1e-6f);
  u16* o = out + (size_t)row*C;
  for (int c = threadIdx.x; c < C; c += 256) o[c] = f2bf(p[c]*r);
}

// ---------------- GEMM v3 (modes 0,1,4): BM=256 BN=128, 32x32x16 MFMA, 3-deep pipeline ----------------
// 8 waves (4M x 2N), per-wave 64x64 = 2x2 tiles of 32x32. D-layout (HW-verified m74/m101):
// col = lane&31, row = (reg&3) + 8*(reg>>2) + 4*(lane>>5).
template<int MODE>
__global__ __launch_bounds__(512, 4) void gemm_kernel(
    const u16* __restrict__ A, const u16* __restrict__ B,
    int M, int N, int K, int nbx, int segw,
    const float* __restrict__ bias, const float* __restrict__ fextra,
    void* __restrict__ outv, u16* __restrict__ out2, u16* __restrict__ out3)
{
  __shared__ __align__(16) u16 As0[256*32];
  __shared__ __align__(16) u16 As1[256*32];
  __shared__ __align__(16) u16 As2[256*32];
  __shared__ __align__(16) u16 Bs0[128*32];
  __shared__ __align__(16) u16 Bs1[128*32];
  __shared__ __align__(16) u16 Bs2[128*32];
  const int tid  = threadIdx.x;
  const int lane = tid & 63;
  const int wv   = tid >> 6;          // 0..7
  const int wr   = wv >> 1, wc = wv & 1;
  const int c32  = lane & 31, g2 = lane >> 5;

  const int nwg  = (int)gridDim.x;
  const int bid  = (int)blockIdx.x;
  const int xcd  = bid & 7;
  const int slot = bid >> 3;
  const int mdep = (nwg >> 3) / nbx;
  const int segsz = mdep * segw;
  const int seg  = slot / segsz;
  const int rem  = slot - seg*segsz;
  const int mi   = rem / segw;
  const int ni   = seg*segw + (rem - mi*segw);
  const long m0 = (long)(xcd*mdep + mi) * 256;
  const long n0 = (long)ni * 128;

  const u16* Ab = A + (size_t)m0*K;
  const u16* Bb = B + (size_t)n0*K;

  const int gsw  = ((lane&3) ^ ((lane>>3)&3)) * 8;
  const int srow = lane >> 2;

  f32x16 acc[2][2];
  #pragma unroll
  for (int i=0;i<2;i++)
    #pragma unroll
    for (int j=0;j<2;j++)
      #pragma unroll
      for (int r=0;r<16;r++) acc[i][j][r] = 0.f;

  auto stage = [&](u16* as, u16* bs, int kt){
    __builtin_amdgcn_global_load_lds(
      (const ASG void*)(Ab + (size_t)(wv*16 + srow)*K + kt + gsw),
      (ASL void*)(as + wv*512), 16, 0, 0);
    __builtin_amdgcn_global_load_lds(
      (const ASG void*)(Ab + (size_t)(128 + wv*16 + srow)*K + kt + gsw),
      (ASL void*)(as + 4096 + wv*512), 16, 0, 0);
    __builtin_amdgcn_global_load_lds(
      (const ASG void*)(Bb + (size_t)(wv*16 + srow)*K + kt + gsw),
      (ASL void*)(bs + wv*512), 16, 0, 0);
  };
  // read slot for rowblock fragments: chunk = 2s+g2, xor = (c32>>1)&3 (row stride 64B)
  auto compute = [&](const u16* as, const u16* bs){
    const int xr = (c32 >> 1) & 3;
    bf16x8s af[2][2], bfr[2][2];
    #pragma unroll
    for (int i=0;i<2;i++)
      #pragma unroll
      for (int s=0;s<2;s++){
        int sl = (2*s + g2) ^ xr;
        af[i][s]  = *(const bf16x8s*)(as + (wr*64 + i*32 + c32)*32 + sl*8);
        bfr[i][s] = *(const bf16x8s*)(bs + (wc*64 + i*32 + c32)*32 + sl*8);
      }
    #pragma unroll
    for (int i=0;i<2;i++)
      #pragma unroll
      for (int j=0;j<2;j++)
        #pragma unroll
        for (int s=0;s<2;s++)
          acc[i][j] = __builtin_amdgcn_mfma_f32_32x32x16_bf16(af[i][s], bfr[j][s], acc[i][j],0,0,0);
  };

  const int NT = K >> 5;   // divisible by 3
  stage(As0, Bs0, 0);
  stage(As1, Bs1, 32);
  asm volatile("s_waitcnt vmcnt(3)" ::: "memory");
  __builtin_amdgcn_s_barrier();
  __builtin_amdgcn_sched_barrier(0);

  for (int t = 0; t < NT; t += 3){
    if (t+2 < NT) stage(As2, Bs2, (t+2)*32);
    compute(As0, Bs0);
    if (t+2 < NT) asm volatile("s_waitcnt vmcnt(3)" ::: "memory");
    else          asm volatile("s_waitcnt vmcnt(0)" ::: "memory");
    __builtin_amdgcn_s_barrier();
    __builtin_amdgcn_sched_barrier(0);
    if (t+3 < NT) stage(As0, Bs0, (t+3)*32);
    compute(As1, Bs1);
    if (t+3 < NT) asm volatile("s_waitcnt vmcnt(3)" ::: "memory");
    else          asm volatile("s_waitcnt vmcnt(0)" ::: "memory");
    __builtin_amdgcn_s_barrier();
    __builtin_amdgcn_sched_barrier(0);
    if (t+4 < NT) stage(As1, Bs1, (t+4)*32);
    compute(As2, Bs2);
    if (t+4 < NT) asm volatile("s_waitcnt vmcnt(3)" ::: "memory");
    else          asm volatile("s_waitcnt vmcnt(0)" ::: "memory");
    __builtin_amdgcn_s_barrier();
    __builtin_amdgcn_sched_barrier(0);
  }

  #pragma unroll
  for (int i=0;i<2;i++){
    #pragma unroll
    for (int j=0;j<2;j++){
      long colg = n0 + wc*64 + j*32 + c32;
      long rowbase = m0 + wr*64 + i*32;
      if (MODE==0){
        int cg = (int)colg;
        int which = cg / 1152;
        int rem2 = cg - which*1152;
        int hh = rem2 / 72, dd = rem2 - hh*72;
        int b = (int)(rowbase >> 10), nb = (int)(rowbase & 1023);
        size_t bh = (size_t)(b*16 + hh);
        float tadd = fextra[(size_t)b*3456 + colg];
        if (which == 2){
          #pragma unroll
          for (int q=0;q<4;q++){
            int n = nb + q*8 + g2*4;
            ushort4 vv;
            vv.x = f2bf(acc[i][j][4*q+0] + tadd);
            vv.y = f2bf(acc[i][j][4*q+1] + tadd);
            vv.z = f2bf(acc[i][j][4*q+2] + tadd);
            vv.w = f2bf(acc[i][j][4*q+3] + tadd);
            *(ushort4*)(out3 + (bh*72 + dd)*1024 + n) = vv;
          }
        } else {
          u16* dst = (which==0) ? (u16*)outv : out2;
          #pragma unroll
          for (int r=0;r<16;r++){
            int n = nb + (r&3) + 8*(r>>2) + 4*g2;
            dst[(bh*1024 + (size_t)n)*72 + dd] = f2bf(acc[i][j][r] + tadd);
          }
        }
      } else {
        #pragma unroll
        for (int r=0;r<16;r++){
          long rowg = rowbase + (r&3) + 8*(r>>2) + 4*g2;
          size_t oi = (size_t)rowg*N + colg;
          float v = acc[i][j][r] + bias[colg] + fextra[oi];
          ((float*)outv)[oi] = v;
        }
      }
    }
  }
}

// ---------------- GEMM 8-phase (gate+up): BM=256 BN=256, BK=64, 32x32x16 MFMA ----------------
// 8 waves (2Mx4N), per-wave 128x64 = 4x2 tiles of 32x32; 2 dbuf x 2 half per operand (128KB).
// Per K-tile: 4 phases = row-blocks; phase p: {4 A ds_reads (+8 B at p0) | stage -> barrier ->
// lgkmcnt(0) -> setprio(1) -> 8 MFMA -> setprio(0) -> [boundary vmcnt(4)] -> barrier}.
__global__ __launch_bounds__(512, 2) void gemm_gu8(
    const u16* __restrict__ A, const u16* __restrict__ B,
    int K, int nbx, int segw,
    const float* __restrict__ bg, const float* __restrict__ bu,
    u16* __restrict__ out)
{
  __shared__ __align__(16) u16 As0[256*64];
  __shared__ __align__(16) u16 Bs0[256*64];
  __shared__ __align__(16) u16 As1[256*64];
  __shared__ __align__(16) u16 Bs1[256*64];
  const int tid  = threadIdx.x;
  const int lane = tid & 63;
  const int wv   = tid >> 6;          // 0..7
  const int wr   = wv >> 2;           // 0..1 (128 rows each)
  const int wc   = wv & 3;            // 0..3 (64 cols each)
  const int c32  = lane & 31, g2 = lane >> 5;

  const int nwg  = (int)gridDim.x;
  const int bid  = (int)blockIdx.x;
  const int xcd  = bid & 7;
  const int slot = bid >> 3;
  const int mdep = (nwg >> 3) / nbx;
  const int segsz = mdep * segw;
  const int seg  = slot / segsz;
  const int rem  = slot - seg*segsz;
  const int mi   = rem / segw;
  const int ni   = seg*segw + (rem - mi*segw);
  const long m0 = (long)(xcd*mdep + mi) * 256;
  const long n0 = (long)ni * 256;

  const u16* Ab = A + (size_t)m0*K;
  const u16* Bb = B + (size_t)n0*K;

  const int srow = tid >> 3;                       // 0..63
  const int q8   = ((tid & 7) ^ (srow & 7)) * 8;   // pre-swizzled source chunk

  auto stageTo = [&](u16* dst, const u16* src, int h, int kt){
    __builtin_amdgcn_global_load_lds(
      (const ASG void*)(src + (size_t)(h*128 + srow)*K + kt + q8),
      (ASL void*)(dst + h*8192 + wv*512), 16, 0, 0);
    __builtin_amdgcn_global_load_lds(
      (const ASG void*)(src + (size_t)(h*128 + 64 + srow)*K + kt + q8),
      (ASL void*)(dst + h*8192 + 4096 + wv*512), 16, 0, 0);
  };

  f32x16 acc[4][2];
  #pragma unroll
  for (int i=0;i<4;i++)
    #pragma unroll
    for (int j=0;j<2;j++)
      #pragma unroll
      for (int r=0;r<16;r++) acc[i][j][r] = 0.f;

  const int x8 = c32 & 7;   // read-side xor (row stride 128B -> slot = chunk ^ (row&7))

  const int NT = K >> 6;   // K-tiles of 64 (K=1152 -> 18, even)

  // prologue: tile0 (A+B) + B(1); wait oldest 8 (tile0), leave B(1)'s 4 in flight
  stageTo(As0, Ab, 0, 0);  stageTo(As0, Ab, 1, 0);
  stageTo(Bs0, Bb, 0, 0);  stageTo(Bs0, Bb, 1, 0);
  stageTo(Bs1, Bb, 0, 64); stageTo(Bs1, Bb, 1, 64);
  asm volatile("s_waitcnt vmcnt(4)" ::: "memory");
  __builtin_amdgcn_s_barrier();
  __builtin_amdgcn_sched_barrier(0);

  auto ktile = [&](const u16* CA, u16* CB, u16* NA, int t){
    const char* aB = (const char*)CA + (size_t)wr*128*128;
    const char* bB = (const char*)CB;
    bf16x8s bfr[2][4];
    #pragma unroll
    for (int p=0;p<4;p++){
      bf16x8s a[4];
      #pragma unroll
      for (int s=0;s<4;s++){
        int sl = (2*s + g2) ^ x8;
        a[s] = *(const bf16x8s*)(aB + (size_t)(p*32 + c32)*128 + sl*16);
      }
      if (p==0){
        #pragma unroll
        for (int j=0;j<2;j++)
          #pragma unroll
          for (int s=0;s<4;s++){
            int sl = (2*s + g2) ^ x8;
            bfr[j][s] = *(const bf16x8s*)(bB + (size_t)(wc*64 + j*32 + c32)*128 + sl*16);
          }
        if (t+1 < NT) stageTo(NA, Ab, 0, (t+1)*64);
      } else if (p==1){
        if (t+1 < NT) stageTo(NA, Ab, 1, (t+1)*64);
      } else if (p==2){
        if (t+2 < NT) stageTo(CB, Bb, 0, (t+2)*64);
      } else {
        if (t+2 < NT) stageTo(CB, Bb, 1, (t+2)*64);
      }
      __builtin_amdgcn_s_barrier();
      asm volatile("s_waitcnt lgkmcnt(0)" ::: "memory");
      __builtin_amdgcn_sched_barrier(0);
      __builtin_amdgcn_s_setprio(1);
      #pragma unroll
      for (int s=0;s<4;s++){
        acc[p][0] = __builtin_amdgcn_mfma_f32_32x32x16_bf16(a[s], bfr[0][s], acc[p][0],0,0,0);
        acc[p][1] = __builtin_amdgcn_mfma_f32_32x32x16_bf16(a[s], bfr[1][s], acc[p][1],0,0,0);
      }
      __builtin_amdgcn_s_setprio(0);
      if (p==3){
        if (t+2 < NT) asm volatile("s_waitcnt vmcnt(4)" ::: "memory");
        else          asm volatile("s_waitcnt vmcnt(0)" ::: "memory");
      }
      __builtin_amdgcn_s_barrier();
      __builtin_amdgcn_sched_barrier(0);
    }
  };

  for (int tp = 0; tp < NT; tp += 2){
    ktile(As0, Bs0, As1, tp);
    ktile(As1, Bs1, As0, tp+1);
  }

  // epilogue: per wave, cols = g-block/u-block pair at hcol = (n0>>1) + wc*32 + c32
  long hcol = (n0>>1) + wc*32 + c32;
  float bgv = bg[hcol], buv = bu[hcol];
  #pragma unroll
  for (int i=0;i<4;i++){
    #pragma unroll
    for (int r=0;r<16;r++){
      long rowg = m0 + wr*128 + i*32 + (r&3) + 8*(r>>2) + 4*g2;
      float gv = acc[i][0][r] + bgv;
      float uv = acc[i][1][r] + buv;
      float hv = (gv/(1.f + __expf(-gv))) * uv;
      out[(size_t)rowg*3072 + hcol] = f2bf(hv);
    }
  }
}

// ---------------- per-(b,h,n): q/k RMS(+weight) + axial RoPE, IN PLACE ----------------
__global__ __launch_bounds__(256) void qkrope_kernel(
    u16* __restrict__ Q, u16* __restrict__ K,
    const float* __restrict__ qn_w, const float* __restrict__ kn_w,
    const float* __restrict__ cos_y, const float* __restrict__ sin_y,
    const float* __restrict__ cos_x, const float* __restrict__ sin_x)
{
  const int gw   = blockIdx.x*4 + (threadIdx.x>>6);   // row over B*H*N = 262144
  const int lane = threadIdx.x & 63;
  const int n = gw & 1023;
  const int d0 = lane*2;
  const bool act = d0 < 72;
  const float scale = 0.11785113019775793f;  // 1/sqrt(72), folded into q

  u16* qp = Q + (size_t)gw*72;
  u16* kp = K + (size_t)gw*72;
  float q0=0,q1=0,k0=0,k1=0,wq0=0,wq1=0,wk0=0,wk1=0;
  if (act){
    q0 = bf2f(qp[d0]); q1 = bf2f(qp[d0+1]);
    k0 = bf2f(kp[d0]); k1 = bf2f(kp[d0+1]);
    wq0 = qn_w[d0]; wq1 = qn_w[d0+1];
    wk0 = kn_w[d0]; wk1 = kn_w[d0+1];
  }
  float ssq = q0*q0 + q1*q1;
  float ssk = k0*k0 + k1*k1;
  #pragma unroll
  for (int d=1; d<64; d<<=1){ ssq += __shfl_xor(ssq,d); ssk += __shfl_xor(ssk,d); }
  const float rq = rsqrtf(ssq*(1.f/72.f) + 1e-6f);
  const float rk = rsqrtf(ssk*(1.f/72.f) + 1e-6f);
  float qn0 = q0*rq*wq0, qn1 = q1*rq*wq1;
  float kn0 = k0*rk*wk0, kn1 = k1*rk*wk1;

  int dh = d0 % 36;
  const bool first = (dh < 18);
  int partner = first ? lane+9 : lane-9;
  if (!act) partner = lane;
  float pq0 = __shfl(qn0, partner), pq1 = __shfl(qn1, partner);
  float pk0 = __shfl(kn0, partner), pk1 = __shfl(kn1, partner);
  if (act){
    const float* cp = (d0 < 36) ? cos_y : cos_x;
    const float* sp = (d0 < 36) ? sin_y : sin_x;
    float c0 = cp[n*36+dh], c1 = cp[n*36+dh+1];
    float s0 = sp[n*36+dh], s1 = sp[n*36+dh+1];
    float sgn = first ? -1.f : 1.f;
    float qo0 = (qn0*c0 + sgn*pq0*s0)*scale, qo1 = (qn1*c1 + sgn*pq1*s1)*scale;
    float ko0 = kn0*c0 + sgn*pk0*s0,         ko1 = kn1*c1 + sgn*pk1*s1;
    *(unsigned*)(qp + d0) = (unsigned)f2bf(qo0) | ((unsigned)f2bf(qo1)<<16);
    *(unsigned*)(kp + d0) = (unsigned)f2bf(ko0) | ((unsigned)f2bf(ko1)<<16);
  }
}

// ---------------- flash attention: 4 waves x 32 q-rows (QBLK=128), KVB=64 ----------------
__global__ __launch_bounds__(256, 3) void attn_kernel(
    const u16* __restrict__ Q, const u16* __restrict__ K,
    const u16* __restrict__ Vt, u16* __restrict__ O)
{
  const int tid  = threadIdx.x;
  const int lane = tid & 63;
  const int wv   = tid >> 6;            // 0..3
  const int g = lane >> 4, c = lane & 15;
  const int bid  = blockIdx.x;
  const int head = (bid >> 6) * 8 + (bid & 7);   // XCD affinity: b%8 == head%8
  const int q0   = ((bid >> 3) & 7) * 128;
  const int b = head >> 4, h = head & 15;

  __shared__ __align__(16) u16 Vlds[80][72];      // [d][k] for current kv-tile; rows 72..79 zero
  __shared__ __align__(16) u16 Plds[8][16][64];   // [wv*2+s][q][k], XOR-swizzled rows

  const bf16x8s zf = {0,0,0,0,0,0,0,0};
  const u16* Kp = K + (size_t)head*1024*72;
  const u16* Qb = Q + ((size_t)head*1024 + q0 + wv*32)*72;
  const char* Vg = (const char*)(Vt + (size_t)head*72*1024);

  bf16x8s qf[2][3];
  #pragma unroll
  for (int s=0;s<2;s++){
    const u16* qrow = Qb + (size_t)(s*16 + c)*72;
    qf[s][0] = *(const bf16x8s*)(qrow + g*8);
    qf[s][1] = *(const bf16x8s*)(qrow + 32 + g*8);
    qf[s][2] = (g==0) ? *(const bf16x8s*)(qrow + 64) : zf;
  }

  f32x4 oacc[2][5];
  float lsum[2] = {0.f, 0.f};
  #pragma unroll
  for (int s=0;s<2;s++)
    #pragma unroll
    for (int c5=0;c5<5;c5++) oacc[s][c5] = (f32x4){0.f,0.f,0.f,0.f};

  char* pb0 = (char*)Plds + (wv*2+0)*2048 + c*128;
  char* pb1 = pb0 + 2048;
  const int swz = (c & 7) << 4;

  int4 vr0, vr1, vr2;
  {
    vr0 = *(const int4*)(Vg + ((tid    )>>3)*2048 + ((tid    )&7)*16);
    vr1 = *(const int4*)(Vg + ((256+tid)>>3)*2048 + ((256+tid)&7)*16);
    if (tid < 64) vr2 = *(const int4*)(Vg + ((512+tid)>>3)*2048 + ((512+tid)&7)*16);
  }
  if (tid < 288) ((u32*)&Vlds[72][0])[tid] = 0u;
  {
    *(int4*)((char*)Vlds + ((tid    )>>3)*144 + ((tid    )&7)*16) = vr0;
    *(int4*)((char*)Vlds + ((256+tid)>>3)*144 + ((256+tid)&7)*16) = vr1;
    if (tid < 64) *(int4*)((char*)Vlds + ((512+tid)>>3)*144 + ((512+tid)&7)*16) = vr2;
  }

  for (int t = 0; t < 16; ++t){
    const int kv0 = t*64;
    __syncthreads();
    if (t < 15){
      const char* vs = Vg + (kv0+64)*2;
      vr0 = *(const int4*)(vs + ((tid    )>>3)*2048 + ((tid    )&7)*16);
      vr1 = *(const int4*)(vs + ((256+tid)>>3)*2048 + ((256+tid)&7)*16);
      if (tid < 64) vr2 = *(const int4*)(vs + ((512+tid)>>3)*2048 + ((512+tid)&7)*16);
    }

    #pragma unroll
    for (int nf=0; nf<4; nf++){
      const u16* krow = Kp + (size_t)(kv0 + nf*16 + c)*72;
      bf16x8s kf0 = *(const bf16x8s*)(krow + g*8);
      bf16x8s kf1 = *(const bf16x8s*)(krow + 32 + g*8);
      bf16x8s kf2 = (g==0) ? *(const bf16x8s*)(krow + 64) : zf;
      #pragma unroll
      for (int s=0;s<2;s++){
        f32x4 sc = (f32x4){0.f,0.f,0.f,0.f};
        sc = __builtin_amdgcn_mfma_f32_16x16x32_bf16(kf0, qf[s][0], sc,0,0,0);
        sc = __builtin_amdgcn_mfma_f32_16x16x32_bf16(kf1, qf[s][1], sc,0,0,0);
        sc = __builtin_amdgcn_mfma_f32_16x16x32_bf16(kf2, qf[s][2], sc,0,0,0);
        float p0 = __expf(sc[0]), p1 = __expf(sc[1]);
        float p2 = __expf(sc[2]), p3 = __expf(sc[3]);
        lsum[s] += (p0+p1) + (p2+p3);
        u32 w0 = (u32)f2bf(p0) | ((u32)f2bf(p1) << 16);
        u32 w1 = (u32)f2bf(p2) | ((u32)f2bf(p3) << 16);
        char* pb = s ? pb1 : pb0;
        int kb = nf*32 + g*8;
        *(u32*)(pb + ( kb      ^ swz)) = w0;
        *(u32*)(pb + ((kb + 4) ^ swz)) = w1;
      }
    }
    asm volatile("" ::: "memory");
    bf16x8s pa[2][2];
    #pragma unroll
    for (int s=0;s<2;s++)
      #pragma unroll
      for (int w2=0;w2<2;w2++)
        pa[s][w2] = *(const bf16x8s*)((s?pb1:pb0) + ((w2*64 + g*16) ^ swz));

    #pragma unroll
    for (int c5=0;c5<5;c5++){
      #pragma unroll
      for (int w2=0;w2<2;w2++){
        bf16x8s vf = *(const bf16x8s*)((const char*)Vlds + (size_t)(c5*16+c)*144 + w2*64 + g*16);
        oacc[0][c5] = __builtin_amdgcn_mfma_f32_16x16x32_bf16(pa[0][w2], vf, oacc[0][c5],0,0,0);
        oacc[1][c5] = __builtin_amdgcn_mfma_f32_16x16x32_bf16(pa[1][w2], vf, oacc[1][c5],0,0,0);
      }
    }

    if (t < 15){
      __syncthreads();
      *(int4*)((char*)Vlds + ((tid    )>>3)*144 + ((tid    )&7)*16) = vr0;
      *(int4*)((char*)Vlds + ((256+tid)>>3)*144 + ((256+tid)&7)*16) = vr1;
      if (tid < 64) *(int4*)((char*)Vlds + ((512+tid)>>3)*144 + ((512+tid)&7)*16) = vr2;
    }
  }

  size_t obase = (size_t)b*1024*1152 + (size_t)h*72;
  #pragma unroll
  for (int s=0;s<2;s++){
    float ls = lsum[s];
    ls += __shfl_xor(ls, 16);
    ls += __shfl_xor(ls, 32);
    float linv[4];
    #pragma unroll
    for (int r=0;r<4;r++) linv[r] = 1.0f / __shfl(ls, 4*g + r);
    #pragma unroll
    for (int c5=0;c5<5;c5++){
      int d = c5*16 + c;
      if (d < 72){
        #pragma unroll
        for (int r=0;r<4;r++){
          int n = q0 + wv*32 + s*16 + 4*g + r;
          O[obase + (size_t)n*1152 + d] = f2bf(oacc[s][c5][r]*linv[r]);
        }
      }
    }
  }
}

extern "C" void kernel_launch(void* const* d_in, const int* in_sizes, int n_in,
                              void* d_out, int out_size, void* d_ws, size_t ws_size,
                              hipStream_t stream) {
  const float* x    = (const float*)d_in[0];
  const float* temb = (const float*)d_in[1];
  const float* cos_y= (const float*)d_in[2];
  const float* sin_y= (const float*)d_in[3];
  const float* cos_x= (const float*)d_in[4];
  const float* sin_x= (const float*)d_in[5];
  const float* Wqkv = (const float*)d_in[6];
  const float* bqkv = (const float*)d_in[7];
  const float* Wt   = (const float*)d_in[8];
  const float* bt   = (const float*)d_in[9];
  const float* Wp   = (const float*)d_in[10];
  const float* bp   = (const float*)d_in[11];
  const float* qn_w = (const float*)d_in[12];
  const float* kn_w = (const float*)d_in[13];
  const float* Wg   = (const float*)d_in[14];
  const float* bg   = (const float*)d_in[15];
  const float* Wu   = (const float*)d_in[16];
  const float* bu   = (const float*)d_in[17];
  const float* Wd   = (const float*)d_in[18];
  const float* bd   = (const float*)d_in[19];

  char* ws = (char*)d_ws;
  size_t off = 0;
  auto alloc = [&](size_t bytes)->void*{
    off = (off + 255) & ~(size_t)255;
    void* p = ws + off; off += bytes; return p;
  };

  u16*   wbuf  = (u16*)alloc((size_t)6144*1152*2);          // shared bf16 weight buffer (max: gate+up interleaved)
  float* tvec  = (float*)alloc((size_t)16*3456*4);
  u16*   xn_bf = (u16*)alloc((size_t)16384*1152*2);         // norm1 out -> o (attn out) -> xn2
  u16*   qt    = (u16*)alloc((size_t)262144*72*2);          // gbuf starts here later
  u16*   kt    = (u16*)alloc((size_t)262144*72*2);
  u16*   vt    = (u16*)alloc((size_t)256*72*1024*2);
  if (off > ws_size) return;   // diagnostic guard: clean fail instead of OOB crash

  u16*   o_bf   = xn_bf;
  u16*   xn2_bf = xn_bf;
  u16*   gbuf   = qt;          // 100.7 MB <= qt+kt+vt region (113.2 MB)
  float* x1     = (float*)d_out;

  // norm1 + temb branch
  rms_kernel<<<16384,256,0,stream>>>(x, xn_bf, 1152);
  temb_kernel<<<864,256,0,stream>>>(temb, Wt, bt, bqkv, tvec);

  // QKV GEMM (scatter epilogue -> qt/kt/vt); 64 m-tiles x 27 n-tiles; segw=9
  cvt_kernel<<<(3456*1152+255)/256,256,0,stream>>>(Wqkv, wbuf, 3456*1152);
  gemm_kernel<0><<<64*27,512,0,stream>>>(
      xn_bf, wbuf, 16384, 3456, 1152, 27, 9, nullptr, tvec, qt, kt, vt);

  // q/k RMS + RoPE in place (q pre-scaled by 1/sqrt(72))
  qkrope_kernel<<<65536,256,0,stream>>>(qt, kt, qn_w, kn_w, cos_y, sin_y, cos_x, sin_x);

  // attention -> o_bf
  attn_kernel<<<2048,256,0,stream>>>(qt, kt, vt, o_bf);

  // proj + residual -> x1 (= d_out, fp32); 64 x 9 tiles; segw=9
  cvt_kernel<<<(1152*1152+255)/256,256,0,stream>>>(Wp, wbuf, 1152*1152);
  gemm_kernel<1><<<64*9,512,0,stream>>>(
      o_bf, wbuf, 16384, 1152, 1152, 9, 9, bp, x, x1, nullptr, nullptr);

  // norm2
  rms_kernel<<<16384,256,0,stream>>>(x1, xn2_bf, 1152);

  // gate+up fused, 8-phase 256x256 kernel (32-granularity g/u interleave); segw=4
  cvt_gu_kernel<<<(6144*1152+255)/256,256,0,stream>>>(Wg, Wu, wbuf);
  gemm_gu8<<<1536,512,0,stream>>>(
      xn2_bf, wbuf, 1152, 24, 4, bg, bu, gbuf);

  // down + residual -> d_out (reads x1 == d_out element-wise, race-free); 64 x 9; segw=3
  cvt_kernel<<<(1152*3072+255)/256,256,0,stream>>>(Wd, wbuf, 1152*3072);
  gemm_kernel<4><<<64*9,512,0,stream>>>(
      gbuf, wbuf, 16384, 1152, 3072, 9, 3, bd, x1, (float*)d_out, nullptr, nullptr);
}

// Round 11
// 983.586 us; speedup vs baseline: 1.0598x; 1.0598x over previous
//
#include <hip/hip_runtime.h>
#include <cstdint>
#include <cstddef>

typedef unsigned short u16;
typedef unsigned int u32;
typedef __attribute__((ext_vector_type(8))) short bf16x8s;
typedef __attribute__((ext_vector_type(4))) float f32x4;

#define ASG __attribute__((address_space(1)))
#define ASL __attribute__((address_space(3)))

__device__ __forceinline__ u16 f2bf(float f){
  union { float f; unsigned u; } v; v.f = f;
  unsigned r = v.u + 0x7FFFu + ((v.u >> 16) & 1u);
  return (u16)(r >> 16);
}
__device__ __forceinline__ float bf2f(u16 h){
  union { unsigned u; float f; } v; v.u = ((unsigned)h) << 16;
  return v.f;
}

// ---------------- fp32 -> bf16 convert ----------------
__global__ __launch_bounds__(256) void cvt_kernel(const float* __restrict__ in,
                                                  u16* __restrict__ out, int n){
  int i = blockIdx.x*256 + threadIdx.x;
  if (i < n) out[i] = f2bf(in[i]);
}

// ---------------- Wg/Wu -> bf16 interleaved in 16-row blocks: out rows [6144][1152] ----------------
__global__ __launch_bounds__(256) void cvt_gu_kernel(const float* __restrict__ Wg,
                                                     const float* __restrict__ Wu,
                                                     u16* __restrict__ out){
  size_t i = (size_t)blockIdx.x*256 + threadIdx.x;   // over 6144*1152
  if (i >= (size_t)6144*1152) return;
  int j = (int)(i / 1152), k = (int)(i % 1152);
  int b16 = j >> 4, w = j & 15;
  int src = (b16 >> 1)*16 + w;
  const float* W = (b16 & 1) ? Wu : Wg;
  out[i] = f2bf(W[(size_t)src*1152 + k]);
}

// ---------------- temb branch: one wave per col, coalesced Wt reads ----------------
__global__ __launch_bounds__(256) void temb_kernel(const float* __restrict__ temb,
                                                   const float* __restrict__ Wt,
                                                   const float* __restrict__ bt,
                                                   const float* __restrict__ bqkv,
                                                   float* __restrict__ tvec){
  const int col  = blockIdx.x*4 + (threadIdx.x>>6);   // 864 blocks x 4 waves = 3456 cols
  const int lane = threadIdx.x & 63;
  const float* wp = Wt + (size_t)col*1152;
  float w[18];
  #pragma unroll
  for (int j=0;j<18;j++) w[j] = wp[lane + j*64];
  float acc[16];
  #pragma unroll
  for (int b=0;b<16;b++) acc[b] = 0.f;
  #pragma unroll
  for (int j=0;j<18;j++){
    const int k = lane + j*64;
    #pragma unroll
    for (int b=0;b<16;b++) acc[b] += w[j]*temb[b*1152 + k];
  }
  #pragma unroll
  for (int b=0;b<16;b++){
    #pragma unroll
    for (int d=1; d<64; d<<=1) acc[b] += __shfl_xor(acc[b], d);
  }
  if (lane == 0){
    float add = bt[col] + bqkv[col];
    #pragma unroll
    for (int b=0;b<16;b++) tvec[(size_t)b*3456 + col] = acc[b] + add;
  }
}

// ---------------- row RMSNorm (no affine), fp32 in -> bf16 out ----------------
__global__ __launch_bounds__(256) void rms_kernel(const float* __restrict__ in,
                                                  u16* __restrict__ out, int C){
  int row = blockIdx.x;
  const float* p = in + (size_t)row*C;
  float ss = 0.f;
  for (int c = threadIdx.x; c < C; c += 256){ float v = p[c]; ss += v*v; }
  #pragma unroll
  for (int d=1; d<64; d<<=1) ss += __shfl_xor(ss, d);
  __shared__ float wsum[4];
  if ((threadIdx.x & 63) == 0) wsum[threadIdx.x>>6] = ss;
  __syncthreads();
  float tot = wsum[0]+wsum[1]+wsum[2]+wsum[3];
  float r = rsqrtf(tot/(float)C + 1e-6f);
  u16* o = out + (size_t)row*C;
  for (int c = threadIdx.x; c < C; c += 256) o[c] = f2bf(p[c]*r);
}

// ---------------- GEMM v2 (QKV): BM=256 BN=128, 16x16x32 MFMA, 3-deep counted pipeline ----------------
template<int MODE>
__global__ __launch_bounds__(512, 4) void gemm_kernel(
    const u16* __restrict__ A, const u16* __restrict__ B,
    int M, int N, int K, int nbx, int segw,
    const float* __restrict__ bias, const float* __restrict__ fextra,
    void* __restrict__ outv, u16* __restrict__ out2, u16* __restrict__ out3)
{
  __shared__ __align__(16) u16 As0[256*32];
  __shared__ __align__(16) u16 As1[256*32];
  __shared__ __align__(16) u16 As2[256*32];
  __shared__ __align__(16) u16 Bs0[128*32];
  __shared__ __align__(16) u16 Bs1[128*32];
  __shared__ __align__(16) u16 Bs2[128*32];
  const int tid  = threadIdx.x;
  const int lane = tid & 63;
  const int wv   = tid >> 6;          // 0..7
  const int wr   = wv >> 1, wc = wv & 1;

  const int nwg  = (int)gridDim.x;
  const int bid  = (int)blockIdx.x;
  const int xcd  = bid & 7;
  const int slot = bid >> 3;
  const int mdep = (nwg >> 3) / nbx;
  const int segsz = mdep * segw;
  const int seg  = slot / segsz;
  const int rem  = slot - seg*segsz;
  const int mi   = rem / segw;
  const int ni   = seg*segw + (rem - mi*segw);
  const long m0 = (long)(xcd*mdep + mi) * 256;
  const long n0 = (long)ni * 128;

  const u16* Ab = A + (size_t)m0*K;
  const u16* Bb = B + (size_t)n0*K;

  const int gsw  = ((lane&3) ^ ((lane>>3)&3)) * 8;
  const int srow = lane >> 2;

  f32x4 acc[4][4];
  #pragma unroll
  for (int i=0;i<4;i++)
    #pragma unroll
    for (int j=0;j<4;j++) acc[i][j] = (f32x4){0.f,0.f,0.f,0.f};

  auto stage = [&](u16* as, u16* bs, int kt){
    __builtin_amdgcn_global_load_lds(
      (const ASG void*)(Ab + (size_t)(wv*16 + srow)*K + kt + gsw),
      (ASL void*)(as + wv*512), 16, 0, 0);
    __builtin_amdgcn_global_load_lds(
      (const ASG void*)(Ab + (size_t)(128 + wv*16 + srow)*K + kt + gsw),
      (ASL void*)(as + 4096 + wv*512), 16, 0, 0);
    __builtin_amdgcn_global_load_lds(
      (const ASG void*)(Bb + (size_t)(wv*16 + srow)*K + kt + gsw),
      (ASL void*)(bs + wv*512), 16, 0, 0);
  };
  auto compute = [&](const u16* as, const u16* bs){
    const int swc = (((lane>>4) ^ ((lane>>1)&3))) * 8;
    const int lc16 = lane & 15;
    bf16x8s af[4], bfr[4];
    #pragma unroll
    for (int i=0;i<4;i++)
      af[i] = *(const bf16x8s*)(as + (wr*64 + i*16 + lc16)*32 + swc);
    #pragma unroll
    for (int j=0;j<4;j++)
      bfr[j] = *(const bf16x8s*)(bs + (wc*64 + j*16 + lc16)*32 + swc);
    #pragma unroll
    for (int i=0;i<4;i++)
      #pragma unroll
      for (int j=0;j<4;j++)
        acc[i][j] = __builtin_amdgcn_mfma_f32_16x16x32_bf16(af[i], bfr[j], acc[i][j], 0,0,0);
  };

  const int NT = K >> 5;   // divisible by 3
  stage(As0, Bs0, 0);
  stage(As1, Bs1, 32);
  asm volatile("s_waitcnt vmcnt(3)" ::: "memory");
  __builtin_amdgcn_s_barrier();
  __builtin_amdgcn_sched_barrier(0);

  for (int t = 0; t < NT; t += 3){
    if (t+2 < NT) stage(As2, Bs2, (t+2)*32);
    compute(As0, Bs0);
    if (t+2 < NT) asm volatile("s_waitcnt vmcnt(3)" ::: "memory");
    else          asm volatile("s_waitcnt vmcnt(0)" ::: "memory");
    __builtin_amdgcn_s_barrier();
    __builtin_amdgcn_sched_barrier(0);
    if (t+3 < NT) stage(As0, Bs0, (t+3)*32);
    compute(As1, Bs1);
    if (t+3 < NT) asm volatile("s_waitcnt vmcnt(3)" ::: "memory");
    else          asm volatile("s_waitcnt vmcnt(0)" ::: "memory");
    __builtin_amdgcn_s_barrier();
    __builtin_amdgcn_sched_barrier(0);
    if (t+4 < NT) stage(As1, Bs1, (t+4)*32);
    compute(As2, Bs2);
    if (t+4 < NT) asm volatile("s_waitcnt vmcnt(3)" ::: "memory");
    else          asm volatile("s_waitcnt vmcnt(0)" ::: "memory");
    __builtin_amdgcn_s_barrier();
    __builtin_amdgcn_sched_barrier(0);
  }

  const int lr = (lane>>4)*4, lc = lane&15;
  #pragma unroll
  for (int i=0;i<4;i++){
    #pragma unroll
    for (int j=0;j<4;j++){
      long colg = n0 + wc*64 + j*16 + lc;
      long rowg0 = m0 + wr*64 + i*16 + lr;
      if (MODE==0){
        int cg = (int)colg;
        int which = cg / 1152;
        int rem2 = cg - which*1152;
        int hh = rem2 / 72, dd = rem2 - hh*72;
        int b = (int)(rowg0 >> 10), n = (int)(rowg0 & 1023);
        size_t bh = (size_t)(b*16 + hh);
        float tadd = fextra[(size_t)b*3456 + colg];
        if (which == 2){
          ushort4 vv;
          vv.x = f2bf(acc[i][j][0] + tadd);
          vv.y = f2bf(acc[i][j][1] + tadd);
          vv.z = f2bf(acc[i][j][2] + tadd);
          vv.w = f2bf(acc[i][j][3] + tadd);
          *(ushort4*)(out3 + (bh*72 + dd)*1024 + n) = vv;
        } else {
          u16* dst = (which==0) ? (u16*)outv : out2;
          #pragma unroll
          for (int r=0;r<4;r++)
            dst[(bh*1024 + (size_t)(n + r))*72 + dd] = f2bf(acc[i][j][r] + tadd);
        }
      } else {
        #pragma unroll
        for (int r=0;r<4;r++){
          long rowg = rowg0 + r;
          float v = acc[i][j][r];
          size_t oi = (size_t)rowg*N + colg;
          v += bias[colg] + fextra[oi];
          ((float*)outv)[oi] = v;
        }
      }
    }
  }
}

// ---------------- GEMM half-tile (proj/down): BM=128 BN=128, 256 thr, 3 blocks/CU ----------------
// Same 3-deep counted-vmcnt schedule + swizzle as v2; fixes the 576-block tail (-> 1152 blocks).
// MODE 1: PROJ (+bias+fextra, f32 out); MODE 4: DOWN (same).
template<int MODE>
__global__ __launch_bounds__(256, 3) void gemm_half(
    const u16* __restrict__ A, const u16* __restrict__ B,
    int M, int N, int K, int nbx, int segw,
    const float* __restrict__ bias, const float* __restrict__ fextra,
    float* __restrict__ outv)
{
  __shared__ __align__(16) u16 As0[128*32];
  __shared__ __align__(16) u16 As1[128*32];
  __shared__ __align__(16) u16 As2[128*32];
  __shared__ __align__(16) u16 Bs0[128*32];
  __shared__ __align__(16) u16 Bs1[128*32];
  __shared__ __align__(16) u16 Bs2[128*32];
  const int tid  = threadIdx.x;
  const int lane = tid & 63;
  const int wv   = tid >> 6;          // 0..3
  const int wr   = wv >> 1, wc = wv & 1;

  const int nwg  = (int)gridDim.x;
  const int bid  = (int)blockIdx.x;
  const int xcd  = bid & 7;
  const int slot = bid >> 3;
  const int mdep = (nwg >> 3) / nbx;
  const int segsz = mdep * segw;
  const int seg  = slot / segsz;
  const int rem  = slot - seg*segsz;
  const int mi   = rem / segw;
  const int ni   = seg*segw + (rem - mi*segw);
  const long m0 = (long)(xcd*mdep + mi) * 128;
  const long n0 = (long)ni * 128;

  const u16* Ab = A + (size_t)m0*K;
  const u16* Bb = B + (size_t)n0*K;

  const int gsw  = ((lane&3) ^ ((lane>>3)&3)) * 8;
  const int srow = lane >> 2;

  f32x4 acc[4][4];
  #pragma unroll
  for (int i=0;i<4;i++)
    #pragma unroll
    for (int j=0;j<4;j++) acc[i][j] = (f32x4){0.f,0.f,0.f,0.f};

  // 4 glds/tile (A rows 0-63, 64-127; B rows 0-63, 64-127), wave wv covers 16 rows each
  auto stage = [&](u16* as, u16* bs, int kt){
    __builtin_amdgcn_global_load_lds(
      (const ASG void*)(Ab + (size_t)(wv*16 + srow)*K + kt + gsw),
      (ASL void*)(as + wv*512), 16, 0, 0);
    __builtin_amdgcn_global_load_lds(
      (const ASG void*)(Ab + (size_t)(64 + wv*16 + srow)*K + kt + gsw),
      (ASL void*)(as + 2048 + wv*512), 16, 0, 0);
    __builtin_amdgcn_global_load_lds(
      (const ASG void*)(Bb + (size_t)(wv*16 + srow)*K + kt + gsw),
      (ASL void*)(bs + wv*512), 16, 0, 0);
    __builtin_amdgcn_global_load_lds(
      (const ASG void*)(Bb + (size_t)(64 + wv*16 + srow)*K + kt + gsw),
      (ASL void*)(bs + 2048 + wv*512), 16, 0, 0);
  };
  auto compute = [&](const u16* as, const u16* bs){
    const int swc = (((lane>>4) ^ ((lane>>1)&3))) * 8;
    const int lc16 = lane & 15;
    bf16x8s af[4], bfr[4];
    #pragma unroll
    for (int i=0;i<4;i++)
      af[i] = *(const bf16x8s*)(as + (wr*64 + i*16 + lc16)*32 + swc);
    #pragma unroll
    for (int j=0;j<4;j++)
      bfr[j] = *(const bf16x8s*)(bs + (wc*64 + j*16 + lc16)*32 + swc);
    #pragma unroll
    for (int i=0;i<4;i++)
      #pragma unroll
      for (int j=0;j<4;j++)
        acc[i][j] = __builtin_amdgcn_mfma_f32_16x16x32_bf16(af[i], bfr[j], acc[i][j], 0,0,0);
  };

  const int NT = K >> 5;   // divisible by 3 (36 or 96)
  stage(As0, Bs0, 0);
  stage(As1, Bs1, 32);
  asm volatile("s_waitcnt vmcnt(4)" ::: "memory");
  __builtin_amdgcn_s_barrier();
  __builtin_amdgcn_sched_barrier(0);

  for (int t = 0; t < NT; t += 3){
    if (t+2 < NT) stage(As2, Bs2, (t+2)*32);
    compute(As0, Bs0);
    if (t+2 < NT) asm volatile("s_waitcnt vmcnt(4)" ::: "memory");
    else          asm volatile("s_waitcnt vmcnt(0)" ::: "memory");
    __builtin_amdgcn_s_barrier();
    __builtin_amdgcn_sched_barrier(0);
    if (t+3 < NT) stage(As0, Bs0, (t+3)*32);
    compute(As1, Bs1);
    if (t+3 < NT) asm volatile("s_waitcnt vmcnt(4)" ::: "memory");
    else          asm volatile("s_waitcnt vmcnt(0)" ::: "memory");
    __builtin_amdgcn_s_barrier();
    __builtin_amdgcn_sched_barrier(0);
    if (t+4 < NT) stage(As1, Bs1, (t+4)*32);
    compute(As2, Bs2);
    if (t+4 < NT) asm volatile("s_waitcnt vmcnt(4)" ::: "memory");
    else          asm volatile("s_waitcnt vmcnt(0)" ::: "memory");
    __builtin_amdgcn_s_barrier();
    __builtin_amdgcn_sched_barrier(0);
  }

  const int lr = (lane>>4)*4, lc = lane&15;
  #pragma unroll
  for (int i=0;i<4;i++){
    #pragma unroll
    for (int j=0;j<4;j++){
      long colg = n0 + wc*64 + j*16 + lc;
      long rowg0 = m0 + wr*64 + i*16 + lr;
      #pragma unroll
      for (int r=0;r<4;r++){
        long rowg = rowg0 + r;
        size_t oi = (size_t)rowg*N + colg;
        outv[oi] = acc[i][j][r] + bias[colg] + fextra[oi];
      }
    }
  }
}

// ---------------- GEMM 8-phase (gate+up): BM=256 BN=256, BK=64, 16x16x32 MFMA ----------------
__global__ __launch_bounds__(512, 2) void gemm_gu8(
    const u16* __restrict__ A, const u16* __restrict__ B,
    int K, int nbx, int segw,
    const float* __restrict__ bg, const float* __restrict__ bu,
    u16* __restrict__ out)
{
  __shared__ __align__(16) u16 As0[256*64];
  __shared__ __align__(16) u16 Bs0[256*64];
  __shared__ __align__(16) u16 As1[256*64];
  __shared__ __align__(16) u16 Bs1[256*64];
  const int tid  = threadIdx.x;
  const int lane = tid & 63;
  const int wv   = tid >> 6;          // 0..7
  const int wr   = wv >> 2;           // 0..1 (128 rows each)
  const int wc   = wv & 3;            // 0..3 (64 cols each)
  const int g = lane >> 4, c = lane & 15;

  const int nwg  = (int)gridDim.x;
  const int bid  = (int)blockIdx.x;
  const int xcd  = bid & 7;
  const int slot = bid >> 3;
  const int mdep = (nwg >> 3) / nbx;
  const int segsz = mdep * segw;
  const int seg  = slot / segsz;
  const int rem  = slot - seg*segsz;
  const int mi   = rem / segw;
  const int ni   = seg*segw + (rem - mi*segw);
  const long m0 = (long)(xcd*mdep + mi) * 256;
  const long n0 = (long)ni * 256;

  const u16* Ab = A + (size_t)m0*K;
  const u16* Bb = B + (size_t)n0*K;

  const int srow = tid >> 3;                       // 0..63
  const int q8   = ((tid & 7) ^ (srow & 7)) * 8;   // pre-swizzled source chunk

  auto stageTo = [&](u16* dst, const u16* src, int h, int kt){
    __builtin_amdgcn_global_load_lds(
      (const ASG void*)(src + (size_t)(h*128 + srow)*K + kt + q8),
      (ASL void*)(dst + h*8192 + wv*512), 16, 0, 0);
    __builtin_amdgcn_global_load_lds(
      (const ASG void*)(src + (size_t)(h*128 + 64 + srow)*K + kt + q8),
      (ASL void*)(dst + h*8192 + 4096 + wv*512), 16, 0, 0);
  };

  f32x4 acc[8][4];
  #pragma unroll
  for (int i=0;i<8;i++)
    #pragma unroll
    for (int j=0;j<4;j++) acc[i][j] = (f32x4){0.f,0.f,0.f,0.f};

  // read-side swizzled 16B-slot offsets (kk = 0,1): slot = (kk*4+g) ^ (c&7)
  const int sw0 = ((g     ) ^ (c & 7)) * 16;
  const int sw1 = ((4 + g ) ^ (c & 7)) * 16;

  const int NT = K >> 6;   // K-tiles of 64 (K=1152 -> 18, even)

  // prologue: tile0 (A+B) + B(1); wait oldest 8 (tile0), leave B(1)'s 4 in flight
  stageTo(As0, Ab, 0, 0);  stageTo(As0, Ab, 1, 0);
  stageTo(Bs0, Bb, 0, 0);  stageTo(Bs0, Bb, 1, 0);
  stageTo(Bs1, Bb, 0, 64); stageTo(Bs1, Bb, 1, 64);
  asm volatile("s_waitcnt vmcnt(4)" ::: "memory");
  __builtin_amdgcn_s_barrier();
  __builtin_amdgcn_sched_barrier(0);

  auto ktile = [&](const u16* CA, u16* CB, u16* NA, int t){
    const char* aB = (const char*)CA + wr*16384;
    const char* bB = (const char*)CB + (wc>>1)*16384;
    bf16x8s bfr[4][2];
    #pragma unroll
    for (int p=0;p<4;p++){
      const int r0 = (2*p)*16 + c;
      const int r1 = r0 + 16;
      bf16x8s a00 = *(const bf16x8s*)(aB + r0*128 + sw0);
      bf16x8s a01 = *(const bf16x8s*)(aB + r0*128 + sw1);
      bf16x8s a10 = *(const bf16x8s*)(aB + r1*128 + sw0);
      bf16x8s a11 = *(const bf16x8s*)(aB + r1*128 + sw1);
      if (p==0){
        #pragma unroll
        for (int j=0;j<4;j++){
          const int br = (wc&1)*64 + j*16 + c;
          bfr[j][0] = *(const bf16x8s*)(bB + br*128 + sw0);
          bfr[j][1] = *(const bf16x8s*)(bB + br*128 + sw1);
        }
        if (t+1 < NT) stageTo(NA, Ab, 0, (t+1)*64);
      } else if (p==1){
        if (t+1 < NT) stageTo(NA, Ab, 1, (t+1)*64);
      } else if (p==2){
        if (t+2 < NT) stageTo(CB, Bb, 0, (t+2)*64);
      } else {
        if (t+2 < NT) stageTo(CB, Bb, 1, (t+2)*64);
      }
      __builtin_amdgcn_s_barrier();
      asm volatile("s_waitcnt lgkmcnt(0)" ::: "memory");
      __builtin_amdgcn_sched_barrier(0);
      __builtin_amdgcn_s_setprio(1);
      #pragma unroll
      for (int j=0;j<4;j++){
        acc[2*p  ][j] = __builtin_amdgcn_mfma_f32_16x16x32_bf16(a00, bfr[j][0], acc[2*p  ][j],0,0,0);
        acc[2*p  ][j] = __builtin_amdgcn_mfma_f32_16x16x32_bf16(a01, bfr[j][1], acc[2*p  ][j],0,0,0);
        acc[2*p+1][j] = __builtin_amdgcn_mfma_f32_16x16x32_bf16(a10, bfr[j][0], acc[2*p+1][j],0,0,0);
        acc[2*p+1][j] = __builtin_amdgcn_mfma_f32_16x16x32_bf16(a11, bfr[j][1], acc[2*p+1][j],0,0,0);
      }
      __builtin_amdgcn_s_setprio(0);
      if (p==3){
        if (t+2 < NT) asm volatile("s_waitcnt vmcnt(4)" ::: "memory");
        else          asm volatile("s_waitcnt vmcnt(0)" ::: "memory");
      }
      __builtin_amdgcn_s_barrier();
      __builtin_amdgcn_sched_barrier(0);
    }
  };

  for (int tp = 0; tp < NT; tp += 2){
    ktile(As0, Bs0, As1, tp);
    ktile(As1, Bs1, As0, tp+1);
  }

  // epilogue: g/u interleaved in 16-col blocks; pairs (j=0,1),(2,3)
  #pragma unroll
  for (int i=0;i<8;i++){
    #pragma unroll
    for (int jp=0;jp<2;jp++){
      long hcol = (n0>>1) + wc*32 + jp*16 + c;
      float bgv = bg[hcol], buv = bu[hcol];
      #pragma unroll
      for (int r=0;r<4;r++){
        long rowg = m0 + wr*128 + i*16 + g*4 + r;
        float gv = acc[i][2*jp  ][r] + bgv;
        float uv = acc[i][2*jp+1][r] + buv;
        float hv = (gv/(1.f + __expf(-gv))) * uv;
        out[(size_t)rowg*3072 + hcol] = f2bf(hv);
      }
    }
  }
}

// ---------------- per-(b,h,n): q/k RMS(+weight) + axial RoPE, IN PLACE ----------------
__global__ __launch_bounds__(256) void qkrope_kernel(
    u16* __restrict__ Q, u16* __restrict__ K,
    const float* __restrict__ qn_w, const float* __restrict__ kn_w,
    const float* __restrict__ cos_y, const float* __restrict__ sin_y,
    const float* __restrict__ cos_x, const float* __restrict__ sin_x)
{
  const int gw   = blockIdx.x*4 + (threadIdx.x>>6);   // row over B*H*N = 262144
  const int lane = threadIdx.x & 63;
  const int n = gw & 1023;
  const int d0 = lane*2;
  const bool act = d0 < 72;
  const float scale = 0.11785113019775793f;  // 1/sqrt(72), folded into q

  u16* qp = Q + (size_t)gw*72;
  u16* kp = K + (size_t)gw*72;
  float q0=0,q1=0,k0=0,k1=0,wq0=0,wq1=0,wk0=0,wk1=0;
  if (act){
    q0 = bf2f(qp[d0]); q1 = bf2f(qp[d0+1]);
    k0 = bf2f(kp[d0]); k1 = bf2f(kp[d0+1]);
    wq0 = qn_w[d0]; wq1 = qn_w[d0+1];
    wk0 = kn_w[d0]; wk1 = kn_w[d0+1];
  }
  float ssq = q0*q0 + q1*q1;
  float ssk = k0*k0 + k1*k1;
  #pragma unroll
  for (int d=1; d<64; d<<=1){ ssq += __shfl_xor(ssq,d); ssk += __shfl_xor(ssk,d); }
  const float rq = rsqrtf(ssq*(1.f/72.f) + 1e-6f);
  const float rk = rsqrtf(ssk*(1.f/72.f) + 1e-6f);
  float qn0 = q0*rq*wq0, qn1 = q1*rq*wq1;
  float kn0 = k0*rk*wk0, kn1 = k1*rk*wk1;

  int dh = d0 % 36;
  const bool first = (dh < 18);
  int partner = first ? lane+9 : lane-9;
  if (!act) partner = lane;
  float pq0 = __shfl(qn0, partner), pq1 = __shfl(qn1, partner);
  float pk0 = __shfl(kn0, partner), pk1 = __shfl(kn1, partner);
  if (act){
    const float* cp = (d0 < 36) ? cos_y : cos_x;
    const float* sp = (d0 < 36) ? sin_y : sin_x;
    float c0 = cp[n*36+dh], c1 = cp[n*36+dh+1];
    float s0 = sp[n*36+dh], s1 = sp[n*36+dh+1];
    float sgn = first ? -1.f : 1.f;
    float qo0 = (qn0*c0 + sgn*pq0*s0)*scale, qo1 = (qn1*c1 + sgn*pq1*s1)*scale;
    float ko0 = kn0*c0 + sgn*pk0*s0,         ko1 = kn1*c1 + sgn*pk1*s1;
    *(unsigned*)(qp + d0) = (unsigned)f2bf(qo0) | ((unsigned)f2bf(qo1)<<16);
    *(unsigned*)(kp + d0) = (unsigned)f2bf(ko0) | ((unsigned)f2bf(ko1)<<16);
  }
}

// ---------------- flash attention: 4 waves x 32 q-rows (QBLK=128), KVB=64 ----------------
__global__ __launch_bounds__(256, 3) void attn_kernel(
    const u16* __restrict__ Q, const u16* __restrict__ K,
    const u16* __restrict__ Vt, u16* __restrict__ O)
{
  const int tid  = threadIdx.x;
  const int lane = tid & 63;
  const int wv   = tid >> 6;            // 0..3
  const int g = lane >> 4, c = lane & 15;
  const int bid  = blockIdx.x;
  const int head = (bid >> 6) * 8 + (bid & 7);   // XCD affinity: b%8 == head%8
  const int q0   = ((bid >> 3) & 7) * 128;
  const int b = head >> 4, h = head & 15;

  __shared__ __align__(16) u16 Vlds[80][72];      // [d][k] for current kv-tile; rows 72..79 zero
  __shared__ __align__(16) u16 Plds[8][16][64];   // [wv*2+s][q][k], XOR-swizzled rows

  const bf16x8s zf = {0,0,0,0,0,0,0,0};
  const u16* Kp = K + (size_t)head*1024*72;
  const u16* Qb = Q + ((size_t)head*1024 + q0 + wv*32)*72;
  const char* Vg = (const char*)(Vt + (size_t)head*72*1024);

  bf16x8s qf[2][3];
  #pragma unroll
  for (int s=0;s<2;s++){
    const u16* qrow = Qb + (size_t)(s*16 + c)*72;
    qf[s][0] = *(const bf16x8s*)(qrow + g*8);
    qf[s][1] = *(const bf16x8s*)(qrow + 32 + g*8);
    qf[s][2] = (g==0) ? *(const bf16x8s*)(qrow + 64) : zf;
  }

  f32x4 oacc[2][5];
  float lsum[2] = {0.f, 0.f};
  #pragma unroll
  for (int s=0;s<2;s++)
    #pragma unroll
    for (int c5=0;c5<5;c5++) oacc[s][c5] = (f32x4){0.f,0.f,0.f,0.f};

  char* pb0 = (char*)Plds + (wv*2+0)*2048 + c*128;
  char* pb1 = pb0 + 2048;
  const int swz = (c & 7) << 4;

  int4 vr0, vr1, vr2;
  {
    vr0 = *(const int4*)(Vg + ((tid    )>>3)*2048 + ((tid    )&7)*16);
    vr1 = *(const int4*)(Vg + ((256+tid)>>3)*2048 + ((256+tid)&7)*16);
    if (tid < 64) vr2 = *(const int4*)(Vg + ((512+tid)>>3)*2048 + ((512+tid)&7)*16);
  }
  if (tid < 288) ((u32*)&Vlds[72][0])[tid] = 0u;
  {
    *(int4*)((char*)Vlds + ((tid    )>>3)*144 + ((tid    )&7)*16) = vr0;
    *(int4*)((char*)Vlds + ((256+tid)>>3)*144 + ((256+tid)&7)*16) = vr1;
    if (tid < 64) *(int4*)((char*)Vlds + ((512+tid)>>3)*144 + ((512+tid)&7)*16) = vr2;
  }

  for (int t = 0; t < 16; ++t){
    const int kv0 = t*64;
    __syncthreads();
    if (t < 15){
      const char* vs = Vg + (kv0+64)*2;
      vr0 = *(const int4*)(vs + ((tid    )>>3)*2048 + ((tid    )&7)*16);
      vr1 = *(const int4*)(vs + ((256+tid)>>3)*2048 + ((256+tid)&7)*16);
      if (tid < 64) vr2 = *(const int4*)(vs + ((512+tid)>>3)*2048 + ((512+tid)&7)*16);
    }

    #pragma unroll
    for (int nf=0; nf<4; nf++){
      const u16* krow = Kp + (size_t)(kv0 + nf*16 + c)*72;
      bf16x8s kf0 = *(const bf16x8s*)(krow + g*8);
      bf16x8s kf1 = *(const bf16x8s*)(krow + 32 + g*8);
      bf16x8s kf2 = (g==0) ? *(const bf16x8s*)(krow + 64) : zf;
      #pragma unroll
      for (int s=0;s<2;s++){
        f32x4 sc = (f32x4){0.f,0.f,0.f,0.f};
        sc = __builtin_amdgcn_mfma_f32_16x16x32_bf16(kf0, qf[s][0], sc,0,0,0);
        sc = __builtin_amdgcn_mfma_f32_16x16x32_bf16(kf1, qf[s][1], sc,0,0,0);
        sc = __builtin_amdgcn_mfma_f32_16x16x32_bf16(kf2, qf[s][2], sc,0,0,0);
        float p0 = __expf(sc[0]), p1 = __expf(sc[1]);
        float p2 = __expf(sc[2]), p3 = __expf(sc[3]);
        lsum[s] += (p0+p1) + (p2+p3);
        u32 w0 = (u32)f2bf(p0) | ((u32)f2bf(p1) << 16);
        u32 w1 = (u32)f2bf(p2) | ((u32)f2bf(p3) << 16);
        char* pb = s ? pb1 : pb0;
        int kb = nf*32 + g*8;
        *(u32*)(pb + ( kb      ^ swz)) = w0;
        *(u32*)(pb + ((kb + 4) ^ swz)) = w1;
      }
    }
    asm volatile("" ::: "memory");
    bf16x8s pa[2][2];
    #pragma unroll
    for (int s=0;s<2;s++)
      #pragma unroll
      for (int w2=0;w2<2;w2++)
        pa[s][w2] = *(const bf16x8s*)((s?pb1:pb0) + ((w2*64 + g*16) ^ swz));

    #pragma unroll
    for (int c5=0;c5<5;c5++){
      #pragma unroll
      for (int w2=0;w2<2;w2++){
        bf16x8s vf = *(const bf16x8s*)((const char*)Vlds + (size_t)(c5*16+c)*144 + w2*64 + g*16);
        oacc[0][c5] = __builtin_amdgcn_mfma_f32_16x16x32_bf16(pa[0][w2], vf, oacc[0][c5],0,0,0);
        oacc[1][c5] = __builtin_amdgcn_mfma_f32_16x16x32_bf16(pa[1][w2], vf, oacc[1][c5],0,0,0);
      }
    }

    if (t < 15){
      __syncthreads();
      *(int4*)((char*)Vlds + ((tid    )>>3)*144 + ((tid    )&7)*16) = vr0;
      *(int4*)((char*)Vlds + ((256+tid)>>3)*144 + ((256+tid)&7)*16) = vr1;
      if (tid < 64) *(int4*)((char*)Vlds + ((512+tid)>>3)*144 + ((512+tid)&7)*16) = vr2;
    }
  }

  size_t obase = (size_t)b*1024*1152 + (size_t)h*72;
  #pragma unroll
  for (int s=0;s<2;s++){
    float ls = lsum[s];
    ls += __shfl_xor(ls, 16);
    ls += __shfl_xor(ls, 32);
    float linv[4];
    #pragma unroll
    for (int r=0;r<4;r++) linv[r] = 1.0f / __shfl(ls, 4*g + r);
    #pragma unroll
    for (int c5=0;c5<5;c5++){
      int d = c5*16 + c;
      if (d < 72){
        #pragma unroll
        for (int r=0;r<4;r++){
          int n = q0 + wv*32 + s*16 + 4*g + r;
          O[obase + (size_t)n*1152 + d] = f2bf(oacc[s][c5][r]*linv[r]);
        }
      }
    }
  }
}

extern "C" void kernel_launch(void* const* d_in, const int* in_sizes, int n_in,
                              void* d_out, int out_size, void* d_ws, size_t ws_size,
                              hipStream_t stream) {
  const float* x    = (const float*)d_in[0];
  const float* temb = (const float*)d_in[1];
  const float* cos_y= (const float*)d_in[2];
  const float* sin_y= (const float*)d_in[3];
  const float* cos_x= (const float*)d_in[4];
  const float* sin_x= (const float*)d_in[5];
  const float* Wqkv = (const float*)d_in[6];
  const float* bqkv = (const float*)d_in[7];
  const float* Wt   = (const float*)d_in[8];
  const float* bt   = (const float*)d_in[9];
  const float* Wp   = (const float*)d_in[10];
  const float* bp   = (const float*)d_in[11];
  const float* qn_w = (const float*)d_in[12];
  const float* kn_w = (const float*)d_in[13];
  const float* Wg   = (const float*)d_in[14];
  const float* bg   = (const float*)d_in[15];
  const float* Wu   = (const float*)d_in[16];
  const float* bu   = (const float*)d_in[17];
  const float* Wd   = (const float*)d_in[18];
  const float* bd   = (const float*)d_in[19];

  char* ws = (char*)d_ws;
  size_t off = 0;
  auto alloc = [&](size_t bytes)->void*{
    off = (off + 255) & ~(size_t)255;
    void* p = ws + off; off += bytes; return p;
  };

  u16*   wbuf  = (u16*)alloc((size_t)6144*1152*2);          // shared bf16 weight buffer (max: gate+up interleaved)
  float* tvec  = (float*)alloc((size_t)16*3456*4);
  u16*   xn_bf = (u16*)alloc((size_t)16384*1152*2);         // norm1 out -> o (attn out) -> xn2
  u16*   qt    = (u16*)alloc((size_t)262144*72*2);          // gbuf starts here later
  u16*   kt    = (u16*)alloc((size_t)262144*72*2);
  u16*   vt    = (u16*)alloc((size_t)256*72*1024*2);
  if (off > ws_size) return;   // diagnostic guard: clean fail instead of OOB crash

  u16*   o_bf   = xn_bf;
  u16*   xn2_bf = xn_bf;
  u16*   gbuf   = qt;          // 100.7 MB <= qt+kt+vt region (113.2 MB)
  float* x1     = (float*)d_out;

  // norm1 + temb branch
  rms_kernel<<<16384,256,0,stream>>>(x, xn_bf, 1152);
  temb_kernel<<<864,256,0,stream>>>(temb, Wt, bt, bqkv, tvec);

  // QKV GEMM (scatter epilogue -> qt/kt/vt); 64 m-tiles x 27 n-tiles; segw=9
  cvt_kernel<<<(3456*1152+255)/256,256,0,stream>>>(Wqkv, wbuf, 3456*1152);
  gemm_kernel<0><<<64*27,512,0,stream>>>(
      xn_bf, wbuf, 16384, 3456, 1152, 27, 9, nullptr, tvec, qt, kt, vt);

  // q/k RMS + RoPE in place (q pre-scaled by 1/sqrt(72))
  qkrope_kernel<<<65536,256,0,stream>>>(qt, kt, qn_w, kn_w, cos_y, sin_y, cos_x, sin_x);

  // attention -> o_bf
  attn_kernel<<<2048,256,0,stream>>>(qt, kt, vt, o_bf);

  // proj + residual -> x1 (= d_out, fp32); 128 m-tiles x 9 n-tiles = 1152 blocks; segw=9
  cvt_kernel<<<(1152*1152+255)/256,256,0,stream>>>(Wp, wbuf, 1152*1152);
  gemm_half<1><<<128*9,256,0,stream>>>(
      o_bf, wbuf, 16384, 1152, 1152, 9, 9, bp, x, x1);

  // norm2
  rms_kernel<<<16384,256,0,stream>>>(x1, xn2_bf, 1152);

  // gate+up fused, 8-phase 256x256 kernel; 64 m x 24 n = 1536 blocks; segw=4
  cvt_gu_kernel<<<(6144*1152+255)/256,256,0,stream>>>(Wg, Wu, wbuf);
  gemm_gu8<<<1536,512,0,stream>>>(
      xn2_bf, wbuf, 1152, 24, 4, bg, bu, gbuf);

  // down + residual -> d_out (reads x1 == d_out element-wise, race-free); 128 x 9 = 1152; segw=3
  cvt_kernel<<<(1152*3072+255)/256,256,0,stream>>>(Wd, wbuf, 1152*3072);
  gemm_half<4><<<128*9,256,0,stream>>>(
      gbuf, wbuf, 16384, 1152, 3072, 9, 3, bd, x1, (float*)d_out);
}

// Round 12
// 921.058 us; speedup vs baseline: 1.1318x; 1.0679x over previous
//
#include <hip/hip_runtime.h>
#include <cstdint>
#include <cstddef>

typedef unsigned short u16;
typedef unsigned int u32;
typedef __attribute__((ext_vector_type(8))) short bf16x8s;
typedef __attribute__((ext_vector_type(4))) float f32x4;

#define ASG __attribute__((address_space(1)))
#define ASL __attribute__((address_space(3)))

__device__ __forceinline__ u16 f2bf(float f){
  union { float f; unsigned u; } v; v.f = f;
  unsigned r = v.u + 0x7FFFu + ((v.u >> 16) & 1u);
  return (u16)(r >> 16);
}
__device__ __forceinline__ float bf2f(u16 h){
  union { unsigned u; float f; } v; v.u = ((unsigned)h) << 16;
  return v.f;
}

// ---------------- fp32 -> bf16 convert, float4 vectorized (n4 = n/4) ----------------
__global__ __launch_bounds__(256) void cvt_kernel(const float* __restrict__ in,
                                                  u16* __restrict__ out, int n4){
  int i = blockIdx.x*256 + threadIdx.x;
  if (i < n4){
    float4 v = ((const float4*)in)[i];
    ushort4 o; o.x = f2bf(v.x); o.y = f2bf(v.y); o.z = f2bf(v.z); o.w = f2bf(v.w);
    ((ushort4*)out)[i] = o;
  }
}

// ---------------- Wg/Wu -> bf16 interleaved in 16-row blocks, float4 vectorized ----------------
__global__ __launch_bounds__(256) void cvt_gu_kernel(const float* __restrict__ Wg,
                                                     const float* __restrict__ Wu,
                                                     u16* __restrict__ out){
  int i4 = blockIdx.x*256 + threadIdx.x;          // over 6144*288
  if (i4 >= 6144*288) return;
  int j = i4 / 288, k4 = i4 - j*288;
  int b16 = j >> 4, w = j & 15;
  int src = (b16 >> 1)*16 + w;
  const float* W = (b16 & 1) ? Wu : Wg;
  float4 v = ((const float4*)W)[(size_t)src*288 + k4];
  ushort4 o; o.x = f2bf(v.x); o.y = f2bf(v.y); o.z = f2bf(v.z); o.w = f2bf(v.w);
  ((ushort4*)out)[i4] = o;
}

// ---------------- temb branch: one wave per col, coalesced Wt reads ----------------
__global__ __launch_bounds__(256) void temb_kernel(const float* __restrict__ temb,
                                                   const float* __restrict__ Wt,
                                                   const float* __restrict__ bt,
                                                   const float* __restrict__ bqkv,
                                                   float* __restrict__ tvec){
  const int col  = blockIdx.x*4 + (threadIdx.x>>6);   // 864 blocks x 4 waves = 3456 cols
  const int lane = threadIdx.x & 63;
  const float* wp = Wt + (size_t)col*1152;
  float w[18];
  #pragma unroll
  for (int j=0;j<18;j++) w[j] = wp[lane + j*64];
  float acc[16];
  #pragma unroll
  for (int b=0;b<16;b++) acc[b] = 0.f;
  #pragma unroll
  for (int j=0;j<18;j++){
    const int k = lane + j*64;
    #pragma unroll
    for (int b=0;b<16;b++) acc[b] += w[j]*temb[b*1152 + k];
  }
  #pragma unroll
  for (int b=0;b<16;b++){
    #pragma unroll
    for (int d=1; d<64; d<<=1) acc[b] += __shfl_xor(acc[b], d);
  }
  if (lane == 0){
    float add = bt[col] + bqkv[col];
    #pragma unroll
    for (int b=0;b<16;b++) tvec[(size_t)b*3456 + col] = acc[b] + add;
  }
}

// ---------------- row RMSNorm (no affine), fp32 in -> bf16 out, float4 vectorized (C=1152) ----------------
__global__ __launch_bounds__(256) void rms_kernel(const float* __restrict__ in,
                                                  u16* __restrict__ out, int C){
  const int tid = threadIdx.x;
  const int row = blockIdx.x;
  const float4* p4 = (const float4*)(in + (size_t)row*1152);   // 288 float4/row
  float4 v0 = p4[tid];
  float4 v1 = {0.f,0.f,0.f,0.f};
  if (tid < 32) v1 = p4[256 + tid];
  float ss = v0.x*v0.x + v0.y*v0.y + v0.z*v0.z + v0.w*v0.w
           + v1.x*v1.x + v1.y*v1.y + v1.z*v1.z + v1.w*v1.w;
  #pragma unroll
  for (int d=1; d<64; d<<=1) ss += __shfl_xor(ss, d);
  __shared__ float wsum[4];
  if ((tid & 63) == 0) wsum[tid>>6] = ss;
  __syncthreads();
  float tot = wsum[0]+wsum[1]+wsum[2]+wsum[3];
  float r = rsqrtf(tot*(1.f/1152.f) + 1e-6f);
  ushort4* o4 = (ushort4*)(out + (size_t)row*1152);
  ushort4 o; o.x=f2bf(v0.x*r); o.y=f2bf(v0.y*r); o.z=f2bf(v0.z*r); o.w=f2bf(v0.w*r);
  o4[tid] = o;
  if (tid < 32){
    ushort4 o1; o1.x=f2bf(v1.x*r); o1.y=f2bf(v1.y*r); o1.z=f2bf(v1.z*r); o1.w=f2bf(v1.w*r);
    o4[256+tid] = o1;
  }
}

// ---------------- GEMM v2 (QKV): BM=256 BN=128, 16x16x32 MFMA, 3-deep counted pipeline ----------------
template<int MODE>
__global__ __launch_bounds__(512, 4) void gemm_kernel(
    const u16* __restrict__ A, const u16* __restrict__ B,
    int M, int N, int K, int nbx, int segw,
    const float* __restrict__ bias, const float* __restrict__ fextra,
    void* __restrict__ outv, u16* __restrict__ out2, u16* __restrict__ out3)
{
  __shared__ __align__(16) u16 As0[256*32];
  __shared__ __align__(16) u16 As1[256*32];
  __shared__ __align__(16) u16 As2[256*32];
  __shared__ __align__(16) u16 Bs0[128*32];
  __shared__ __align__(16) u16 Bs1[128*32];
  __shared__ __align__(16) u16 Bs2[128*32];
  const int tid  = threadIdx.x;
  const int lane = tid & 63;
  const int wv   = tid >> 6;          // 0..7
  const int wr   = wv >> 1, wc = wv & 1;

  const int nwg  = (int)gridDim.x;
  const int bid  = (int)blockIdx.x;
  const int xcd  = bid & 7;
  const int slot = bid >> 3;
  const int mdep = (nwg >> 3) / nbx;
  const int segsz = mdep * segw;
  const int seg  = slot / segsz;
  const int rem  = slot - seg*segsz;
  const int mi   = rem / segw;
  const int ni   = seg*segw + (rem - mi*segw);
  const long m0 = (long)(xcd*mdep + mi) * 256;
  const long n0 = (long)ni * 128;

  const u16* Ab = A + (size_t)m0*K;
  const u16* Bb = B + (size_t)n0*K;

  const int gsw  = ((lane&3) ^ ((lane>>3)&3)) * 8;
  const int srow = lane >> 2;

  f32x4 acc[4][4];
  #pragma unroll
  for (int i=0;i<4;i++)
    #pragma unroll
    for (int j=0;j<4;j++) acc[i][j] = (f32x4){0.f,0.f,0.f,0.f};

  auto stage = [&](u16* as, u16* bs, int kt){
    __builtin_amdgcn_global_load_lds(
      (const ASG void*)(Ab + (size_t)(wv*16 + srow)*K + kt + gsw),
      (ASL void*)(as + wv*512), 16, 0, 0);
    __builtin_amdgcn_global_load_lds(
      (const ASG void*)(Ab + (size_t)(128 + wv*16 + srow)*K + kt + gsw),
      (ASL void*)(as + 4096 + wv*512), 16, 0, 0);
    __builtin_amdgcn_global_load_lds(
      (const ASG void*)(Bb + (size_t)(wv*16 + srow)*K + kt + gsw),
      (ASL void*)(bs + wv*512), 16, 0, 0);
  };
  auto compute = [&](const u16* as, const u16* bs){
    const int swc = (((lane>>4) ^ ((lane>>1)&3))) * 8;
    const int lc16 = lane & 15;
    bf16x8s af[4], bfr[4];
    #pragma unroll
    for (int i=0;i<4;i++)
      af[i] = *(const bf16x8s*)(as + (wr*64 + i*16 + lc16)*32 + swc);
    #pragma unroll
    for (int j=0;j<4;j++)
      bfr[j] = *(const bf16x8s*)(bs + (wc*64 + j*16 + lc16)*32 + swc);
    #pragma unroll
    for (int i=0;i<4;i++)
      #pragma unroll
      for (int j=0;j<4;j++)
        acc[i][j] = __builtin_amdgcn_mfma_f32_16x16x32_bf16(af[i], bfr[j], acc[i][j], 0,0,0);
  };

  const int NT = K >> 5;   // divisible by 3
  stage(As0, Bs0, 0);
  stage(As1, Bs1, 32);
  asm volatile("s_waitcnt vmcnt(3)" ::: "memory");
  __builtin_amdgcn_s_barrier();
  __builtin_amdgcn_sched_barrier(0);

  for (int t = 0; t < NT; t += 3){
    if (t+2 < NT) stage(As2, Bs2, (t+2)*32);
    compute(As0, Bs0);
    if (t+2 < NT) asm volatile("s_waitcnt vmcnt(3)" ::: "memory");
    else          asm volatile("s_waitcnt vmcnt(0)" ::: "memory");
    __builtin_amdgcn_s_barrier();
    __builtin_amdgcn_sched_barrier(0);
    if (t+3 < NT) stage(As0, Bs0, (t+3)*32);
    compute(As1, Bs1);
    if (t+3 < NT) asm volatile("s_waitcnt vmcnt(3)" ::: "memory");
    else          asm volatile("s_waitcnt vmcnt(0)" ::: "memory");
    __builtin_amdgcn_s_barrier();
    __builtin_amdgcn_sched_barrier(0);
    if (t+4 < NT) stage(As1, Bs1, (t+4)*32);
    compute(As2, Bs2);
    if (t+4 < NT) asm volatile("s_waitcnt vmcnt(3)" ::: "memory");
    else          asm volatile("s_waitcnt vmcnt(0)" ::: "memory");
    __builtin_amdgcn_s_barrier();
    __builtin_amdgcn_sched_barrier(0);
  }

  const int lr = (lane>>4)*4, lc = lane&15;
  #pragma unroll
  for (int i=0;i<4;i++){
    #pragma unroll
    for (int j=0;j<4;j++){
      long colg = n0 + wc*64 + j*16 + lc;
      long rowg0 = m0 + wr*64 + i*16 + lr;
      if (MODE==0){
        int cg = (int)colg;
        int which = cg / 1152;
        int rem2 = cg - which*1152;
        int hh = rem2 / 72, dd = rem2 - hh*72;
        int b = (int)(rowg0 >> 10), n = (int)(rowg0 & 1023);
        size_t bh = (size_t)(b*16 + hh);
        float tadd = fextra[(size_t)b*3456 + colg];
        if (which == 2){
          ushort4 vv;
          vv.x = f2bf(acc[i][j][0] + tadd);
          vv.y = f2bf(acc[i][j][1] + tadd);
          vv.z = f2bf(acc[i][j][2] + tadd);
          vv.w = f2bf(acc[i][j][3] + tadd);
          *(ushort4*)(out3 + (bh*72 + dd)*1024 + n) = vv;
        } else {
          u16* dst = (which==0) ? (u16*)outv : out2;
          #pragma unroll
          for (int r=0;r<4;r++)
            dst[(bh*1024 + (size_t)(n + r))*72 + dd] = f2bf(acc[i][j][r] + tadd);
        }
      } else {
        #pragma unroll
        for (int r=0;r<4;r++){
          long rowg = rowg0 + r;
          float v = acc[i][j][r];
          size_t oi = (size_t)rowg*N + colg;
          v += bias[colg] + fextra[oi];
          ((float*)outv)[oi] = v;
        }
      }
    }
  }
}

// ---------------- GEMM half-tile (proj/down): BM=128 BN=128, 256 thr, 3 blocks/CU ----------------
template<int MODE>
__global__ __launch_bounds__(256, 3) void gemm_half(
    const u16* __restrict__ A, const u16* __restrict__ B,
    int M, int N, int K, int nbx, int segw,
    const float* __restrict__ bias, const float* __restrict__ fextra,
    float* __restrict__ outv)
{
  __shared__ __align__(16) u16 As0[128*32];
  __shared__ __align__(16) u16 As1[128*32];
  __shared__ __align__(16) u16 As2[128*32];
  __shared__ __align__(16) u16 Bs0[128*32];
  __shared__ __align__(16) u16 Bs1[128*32];
  __shared__ __align__(16) u16 Bs2[128*32];
  const int tid  = threadIdx.x;
  const int lane = tid & 63;
  const int wv   = tid >> 6;          // 0..3
  const int wr   = wv >> 1, wc = wv & 1;

  const int nwg  = (int)gridDim.x;
  const int bid  = (int)blockIdx.x;
  const int xcd  = bid & 7;
  const int slot = bid >> 3;
  const int mdep = (nwg >> 3) / nbx;
  const int segsz = mdep * segw;
  const int seg  = slot / segsz;
  const int rem  = slot - seg*segsz;
  const int mi   = rem / segw;
  const int ni   = seg*segw + (rem - mi*segw);
  const long m0 = (long)(xcd*mdep + mi) * 128;
  const long n0 = (long)ni * 128;

  const u16* Ab = A + (size_t)m0*K;
  const u16* Bb = B + (size_t)n0*K;

  const int gsw  = ((lane&3) ^ ((lane>>3)&3)) * 8;
  const int srow = lane >> 2;

  f32x4 acc[4][4];
  #pragma unroll
  for (int i=0;i<4;i++)
    #pragma unroll
    for (int j=0;j<4;j++) acc[i][j] = (f32x4){0.f,0.f,0.f,0.f};

  auto stage = [&](u16* as, u16* bs, int kt){
    __builtin_amdgcn_global_load_lds(
      (const ASG void*)(Ab + (size_t)(wv*16 + srow)*K + kt + gsw),
      (ASL void*)(as + wv*512), 16, 0, 0);
    __builtin_amdgcn_global_load_lds(
      (const ASG void*)(Ab + (size_t)(64 + wv*16 + srow)*K + kt + gsw),
      (ASL void*)(as + 2048 + wv*512), 16, 0, 0);
    __builtin_amdgcn_global_load_lds(
      (const ASG void*)(Bb + (size_t)(wv*16 + srow)*K + kt + gsw),
      (ASL void*)(bs + wv*512), 16, 0, 0);
    __builtin_amdgcn_global_load_lds(
      (const ASG void*)(Bb + (size_t)(64 + wv*16 + srow)*K + kt + gsw),
      (ASL void*)(bs + 2048 + wv*512), 16, 0, 0);
  };
  auto compute = [&](const u16* as, const u16* bs){
    const int swc = (((lane>>4) ^ ((lane>>1)&3))) * 8;
    const int lc16 = lane & 15;
    bf16x8s af[4], bfr[4];
    #pragma unroll
    for (int i=0;i<4;i++)
      af[i] = *(const bf16x8s*)(as + (wr*64 + i*16 + lc16)*32 + swc);
    #pragma unroll
    for (int j=0;j<4;j++)
      bfr[j] = *(const bf16x8s*)(bs + (wc*64 + j*16 + lc16)*32 + swc);
    #pragma unroll
    for (int i=0;i<4;i++)
      #pragma unroll
      for (int j=0;j<4;j++)
        acc[i][j] = __builtin_amdgcn_mfma_f32_16x16x32_bf16(af[i], bfr[j], acc[i][j], 0,0,0);
  };

  const int NT = K >> 5;   // divisible by 3 (36 or 96)
  stage(As0, Bs0, 0);
  stage(As1, Bs1, 32);
  asm volatile("s_waitcnt vmcnt(4)" ::: "memory");
  __builtin_amdgcn_s_barrier();
  __builtin_amdgcn_sched_barrier(0);

  for (int t = 0; t < NT; t += 3){
    if (t+2 < NT) stage(As2, Bs2, (t+2)*32);
    compute(As0, Bs0);
    if (t+2 < NT) asm volatile("s_waitcnt vmcnt(4)" ::: "memory");
    else          asm volatile("s_waitcnt vmcnt(0)" ::: "memory");
    __builtin_amdgcn_s_barrier();
    __builtin_amdgcn_sched_barrier(0);
    if (t+3 < NT) stage(As0, Bs0, (t+3)*32);
    compute(As1, Bs1);
    if (t+3 < NT) asm volatile("s_waitcnt vmcnt(4)" ::: "memory");
    else          asm volatile("s_waitcnt vmcnt(0)" ::: "memory");
    __builtin_amdgcn_s_barrier();
    __builtin_amdgcn_sched_barrier(0);
    if (t+4 < NT) stage(As1, Bs1, (t+4)*32);
    compute(As2, Bs2);
    if (t+4 < NT) asm volatile("s_waitcnt vmcnt(4)" ::: "memory");
    else          asm volatile("s_waitcnt vmcnt(0)" ::: "memory");
    __builtin_amdgcn_s_barrier();
    __builtin_amdgcn_sched_barrier(0);
  }

  const int lr = (lane>>4)*4, lc = lane&15;
  #pragma unroll
  for (int i=0;i<4;i++){
    #pragma unroll
    for (int j=0;j<4;j++){
      long colg = n0 + wc*64 + j*16 + lc;
      long rowg0 = m0 + wr*64 + i*16 + lr;
      #pragma unroll
      for (int r=0;r<4;r++){
        long rowg = rowg0 + r;
        size_t oi = (size_t)rowg*N + colg;
        outv[oi] = acc[i][j][r] + bias[colg] + fextra[oi];
      }
    }
  }
}

// ---------------- GEMM 8-wave 2-chunk (gate+up): BM=256 BN=256, BK=64 ----------------
// Per K-tile (2 chunks, 2 barriers, 2 lgkm):
//  chunk0: ds_read B(all 8) + A strips 0-3; stage A(t+1) h0+h1; lgkm0; BARRIER;
//          stage B(t+2) h0 (CB reads done); 32 MFMA.
//  chunk1: ds_read A strips 4-7 (CA never written this tile -> no barrier);
//          stage B(t+2) h1; lgkm0; 32 MFMA; vmcnt(4); BARRIER.
// Stage order A(t+1) before B(t+2) => end vmcnt(4) provably retires A(t+1)
// (queue: [B(t+1):4][A(t+1):4][B(t+2):4]).
__global__ __launch_bounds__(512, 2) void gemm_gu8(
    const u16* __restrict__ A, const u16* __restrict__ B,
    int K, int nbx, int segw,
    const float* __restrict__ bg, const float* __restrict__ bu,
    u16* __restrict__ out)
{
  __shared__ __align__(16) u16 As0[256*64];
  __shared__ __align__(16) u16 Bs0[256*64];
  __shared__ __align__(16) u16 As1[256*64];
  __shared__ __align__(16) u16 Bs1[256*64];
  const int tid  = threadIdx.x;
  const int lane = tid & 63;
  const int wv   = tid >> 6;          // 0..7
  const int wr   = wv >> 2;           // 0..1 (128 rows each)
  const int wc   = wv & 3;            // 0..3 (64 cols each)
  const int g = lane >> 4, c = lane & 15;

  const int nwg  = (int)gridDim.x;
  const int bid  = (int)blockIdx.x;
  const int xcd  = bid & 7;
  const int slot = bid >> 3;
  const int mdep = (nwg >> 3) / nbx;
  const int segsz = mdep * segw;
  const int seg  = slot / segsz;
  const int rem  = slot - seg*segsz;
  const int mi   = rem / segw;
  const int ni   = seg*segw + (rem - mi*segw);
  const long m0 = (long)(xcd*mdep + mi) * 256;
  const long n0 = (long)ni * 256;

  const u16* Ab = A + (size_t)m0*K;
  const u16* Bb = B + (size_t)n0*K;

  const int srow = tid >> 3;                       // 0..63
  const int q8   = ((tid & 7) ^ (srow & 7)) * 8;   // pre-swizzled source chunk

  auto stageTo = [&](u16* dst, const u16* src, int h, int kt){
    __builtin_amdgcn_global_load_lds(
      (const ASG void*)(src + (size_t)(h*128 + srow)*K + kt + q8),
      (ASL void*)(dst + h*8192 + wv*512), 16, 0, 0);
    __builtin_amdgcn_global_load_lds(
      (const ASG void*)(src + (size_t)(h*128 + 64 + srow)*K + kt + q8),
      (ASL void*)(dst + h*8192 + 4096 + wv*512), 16, 0, 0);
  };

  f32x4 acc[8][4];
  #pragma unroll
  for (int i=0;i<8;i++)
    #pragma unroll
    for (int j=0;j<4;j++) acc[i][j] = (f32x4){0.f,0.f,0.f,0.f};

  // read-side swizzled 16B-slot offsets (kk = 0,1): slot = (kk*4+g) ^ (c&7)
  const int sw0 = ((g     ) ^ (c & 7)) * 16;
  const int sw1 = ((4 + g ) ^ (c & 7)) * 16;

  const int NT = K >> 6;   // K-tiles of 64 (K=1152 -> 18, even)

  // prologue: tile0 (A+B) + B(1); wait oldest 8 (tile0), leave B(1)'s 4 in flight
  stageTo(As0, Ab, 0, 0);  stageTo(As0, Ab, 1, 0);
  stageTo(Bs0, Bb, 0, 0);  stageTo(Bs0, Bb, 1, 0);
  stageTo(Bs1, Bb, 0, 64); stageTo(Bs1, Bb, 1, 64);
  asm volatile("s_waitcnt vmcnt(4)" ::: "memory");
  __builtin_amdgcn_s_barrier();
  __builtin_amdgcn_sched_barrier(0);

  auto ktile = [&](const u16* CA, u16* CB, u16* NA, int t){
    const char* aB = (const char*)CA + wr*16384;
    const char* bB = (const char*)CB + (wc>>1)*16384;
    // ---- chunk 0: read B(all) + A strips 0-3 ----
    bf16x8s bfr[4][2], a0[4][2];
    #pragma unroll
    for (int j=0;j<4;j++){
      const int br = (wc&1)*64 + j*16 + c;
      bfr[j][0] = *(const bf16x8s*)(bB + br*128 + sw0);
      bfr[j][1] = *(const bf16x8s*)(bB + br*128 + sw1);
    }
    #pragma unroll
    for (int i=0;i<4;i++){
      const int ar = i*16 + c;
      a0[i][0] = *(const bf16x8s*)(aB + ar*128 + sw0);
      a0[i][1] = *(const bf16x8s*)(aB + ar*128 + sw1);
    }
    if (t+1 < NT){ stageTo(NA, Ab, 0, (t+1)*64); stageTo(NA, Ab, 1, (t+1)*64); }
    asm volatile("s_waitcnt lgkmcnt(0)" ::: "memory");
    __builtin_amdgcn_sched_barrier(0);
    __builtin_amdgcn_s_barrier();          // all waves' CB reads complete
    if (t+2 < NT) stageTo(CB, Bb, 0, (t+2)*64);
    __builtin_amdgcn_s_setprio(1);
    #pragma unroll
    for (int i=0;i<4;i++)
      #pragma unroll
      for (int j=0;j<4;j++){
        acc[i][j] = __builtin_amdgcn_mfma_f32_16x16x32_bf16(a0[i][0], bfr[j][0], acc[i][j],0,0,0);
        acc[i][j] = __builtin_amdgcn_mfma_f32_16x16x32_bf16(a0[i][1], bfr[j][1], acc[i][j],0,0,0);
      }
    __builtin_amdgcn_s_setprio(0);
    // ---- chunk 1: read A strips 4-7 (CA not written this tile: no barrier) ----
    bf16x8s a1[4][2];
    #pragma unroll
    for (int i=0;i<4;i++){
      const int ar = (4+i)*16 + c;
      a1[i][0] = *(const bf16x8s*)(aB + ar*128 + sw0);
      a1[i][1] = *(const bf16x8s*)(aB + ar*128 + sw1);
    }
    if (t+2 < NT) stageTo(CB, Bb, 1, (t+2)*64);
    asm volatile("s_waitcnt lgkmcnt(0)" ::: "memory");
    __builtin_amdgcn_sched_barrier(0);
    __builtin_amdgcn_s_setprio(1);
    #pragma unroll
    for (int i=0;i<4;i++)
      #pragma unroll
      for (int j=0;j<4;j++){
        acc[4+i][j] = __builtin_amdgcn_mfma_f32_16x16x32_bf16(a1[i][0], bfr[j][0], acc[4+i][j],0,0,0);
        acc[4+i][j] = __builtin_amdgcn_mfma_f32_16x16x32_bf16(a1[i][1], bfr[j][1], acc[4+i][j],0,0,0);
      }
    __builtin_amdgcn_s_setprio(0);
    if (t+2 < NT) asm volatile("s_waitcnt vmcnt(4)" ::: "memory");
    else          asm volatile("s_waitcnt vmcnt(0)" ::: "memory");
    __builtin_amdgcn_s_barrier();
    __builtin_amdgcn_sched_barrier(0);
  };

  for (int tp = 0; tp < NT; tp += 2){
    ktile(As0, Bs0, As1, tp);
    ktile(As1, Bs1, As0, tp+1);
  }

  // epilogue: g/u interleaved in 16-col blocks; pairs (j=0,1),(2,3)
  #pragma unroll
  for (int i=0;i<8;i++){
    #pragma unroll
    for (int jp=0;jp<2;jp++){
      long hcol = (n0>>1) + wc*32 + jp*16 + c;
      float bgv = bg[hcol], buv = bu[hcol];
      #pragma unroll
      for (int r=0;r<4;r++){
        long rowg = m0 + wr*128 + i*16 + g*4 + r;
        float gv = acc[i][2*jp  ][r] + bgv;
        float uv = acc[i][2*jp+1][r] + buv;
        float hv = (gv/(1.f + __expf(-gv))) * uv;
        out[(size_t)rowg*3072 + hcol] = f2bf(hv);
      }
    }
  }
}

// ---------------- per-(b,h,n): q/k RMS(+weight) + axial RoPE, IN PLACE ----------------
__global__ __launch_bounds__(256) void qkrope_kernel(
    u16* __restrict__ Q, u16* __restrict__ K,
    const float* __restrict__ qn_w, const float* __restrict__ kn_w,
    const float* __restrict__ cos_y, const float* __restrict__ sin_y,
    const float* __restrict__ cos_x, const float* __restrict__ sin_x)
{
  const int gw   = blockIdx.x*4 + (threadIdx.x>>6);   // row over B*H*N = 262144
  const int lane = threadIdx.x & 63;
  const int n = gw & 1023;
  const int d0 = lane*2;
  const bool act = d0 < 72;
  const float scale = 0.11785113019775793f;  // 1/sqrt(72), folded into q

  u16* qp = Q + (size_t)gw*72;
  u16* kp = K + (size_t)gw*72;
  float q0=0,q1=0,k0=0,k1=0,wq0=0,wq1=0,wk0=0,wk1=0;
  if (act){
    q0 = bf2f(qp[d0]); q1 = bf2f(qp[d0+1]);
    k0 = bf2f(kp[d0]); k1 = bf2f(kp[d0+1]);
    wq0 = qn_w[d0]; wq1 = qn_w[d0+1];
    wk0 = kn_w[d0]; wk1 = kn_w[d0+1];
  }
  float ssq = q0*q0 + q1*q1;
  float ssk = k0*k0 + k1*k1;
  #pragma unroll
  for (int d=1; d<64; d<<=1){ ssq += __shfl_xor(ssq,d); ssk += __shfl_xor(ssk,d); }
  const float rq = rsqrtf(ssq*(1.f/72.f) + 1e-6f);
  const float rk = rsqrtf(ssk*(1.f/72.f) + 1e-6f);
  float qn0 = q0*rq*wq0, qn1 = q1*rq*wq1;
  float kn0 = k0*rk*wk0, kn1 = k1*rk*wk1;

  int dh = d0 % 36;
  const bool first = (dh < 18);
  int partner = first ? lane+9 : lane-9;
  if (!act) partner = lane;
  float pq0 = __shfl(qn0, partner), pq1 = __shfl(qn1, partner);
  float pk0 = __shfl(kn0, partner), pk1 = __shfl(kn1, partner);
  if (act){
    const float* cp = (d0 < 36) ? cos_y : cos_x;
    const float* sp = (d0 < 36) ? sin_y : sin_x;
    float c0 = cp[n*36+dh], c1 = cp[n*36+dh+1];
    float s0 = sp[n*36+dh], s1 = sp[n*36+dh+1];
    float sgn = first ? -1.f : 1.f;
    float qo0 = (qn0*c0 + sgn*pq0*s0)*scale, qo1 = (qn1*c1 + sgn*pq1*s1)*scale;
    float ko0 = kn0*c0 + sgn*pk0*s0,         ko1 = kn1*c1 + sgn*pk1*s1;
    *(unsigned*)(qp + d0) = (unsigned)f2bf(qo0) | ((unsigned)f2bf(qo1)<<16);
    *(unsigned*)(kp + d0) = (unsigned)f2bf(ko0) | ((unsigned)f2bf(ko1)<<16);
  }
}

// ---------------- flash attention: 4 waves x 32 q-rows (QBLK=128), KVB=64 ----------------
__global__ __launch_bounds__(256, 3) void attn_kernel(
    const u16* __restrict__ Q, const u16* __restrict__ K,
    const u16* __restrict__ Vt, u16* __restrict__ O)
{
  const int tid  = threadIdx.x;
  const int lane = tid & 63;
  const int wv   = tid >> 6;            // 0..3
  const int g = lane >> 4, c = lane & 15;
  const int bid  = blockIdx.x;
  const int head = (bid >> 6) * 8 + (bid & 7);   // XCD affinity: b%8 == head%8
  const int q0   = ((bid >> 3) & 7) * 128;
  const int b = head >> 4, h = head & 15;

  __shared__ __align__(16) u16 Vlds[80][72];      // [d][k] for current kv-tile; rows 72..79 zero
  __shared__ __align__(16) u16 Plds[8][16][64];   // [wv*2+s][q][k], XOR-swizzled rows

  const bf16x8s zf = {0,0,0,0,0,0,0,0};
  const u16* Kp = K + (size_t)head*1024*72;
  const u16* Qb = Q + ((size_t)head*1024 + q0 + wv*32)*72;
  const char* Vg = (const char*)(Vt + (size_t)head*72*1024);

  bf16x8s qf[2][3];
  #pragma unroll
  for (int s=0;s<2;s++){
    const u16* qrow = Qb + (size_t)(s*16 + c)*72;
    qf[s][0] = *(const bf16x8s*)(qrow + g*8);
    qf[s][1] = *(const bf16x8s*)(qrow + 32 + g*8);
    qf[s][2] = (g==0) ? *(const bf16x8s*)(qrow + 64) : zf;
  }

  f32x4 oacc[2][5];
  float lsum[2] = {0.f, 0.f};
  #pragma unroll
  for (int s=0;s<2;s++)
    #pragma unroll
    for (int c5=0;c5<5;c5++) oacc[s][c5] = (f32x4){0.f,0.f,0.f,0.f};

  char* pb0 = (char*)Plds + (wv*2+0)*2048 + c*128;
  char* pb1 = pb0 + 2048;
  const int swz = (c & 7) << 4;

  int4 vr0, vr1, vr2;
  {
    vr0 = *(const int4*)(Vg + ((tid    )>>3)*2048 + ((tid    )&7)*16);
    vr1 = *(const int4*)(Vg + ((256+tid)>>3)*2048 + ((256+tid)&7)*16);
    if (tid < 64) vr2 = *(const int4*)(Vg + ((512+tid)>>3)*2048 + ((512+tid)&7)*16);
  }
  if (tid < 288) ((u32*)&Vlds[72][0])[tid] = 0u;
  {
    *(int4*)((char*)Vlds + ((tid    )>>3)*144 + ((tid    )&7)*16) = vr0;
    *(int4*)((char*)Vlds + ((256+tid)>>3)*144 + ((256+tid)&7)*16) = vr1;
    if (tid < 64) *(int4*)((char*)Vlds + ((512+tid)>>3)*144 + ((512+tid)&7)*16) = vr2;
  }

  for (int t = 0; t < 16; ++t){
    const int kv0 = t*64;
    __syncthreads();
    if (t < 15){
      const char* vs = Vg + (kv0+64)*2;
      vr0 = *(const int4*)(vs + ((tid    )>>3)*2048 + ((tid    )&7)*16);
      vr1 = *(const int4*)(vs + ((256+tid)>>3)*2048 + ((256+tid)&7)*16);
      if (tid < 64) vr2 = *(const int4*)(vs + ((512+tid)>>3)*2048 + ((512+tid)&7)*16);
    }

    #pragma unroll
    for (int nf=0; nf<4; nf++){
      const u16* krow = Kp + (size_t)(kv0 + nf*16 + c)*72;
      bf16x8s kf0 = *(const bf16x8s*)(krow + g*8);
      bf16x8s kf1 = *(const bf16x8s*)(krow + 32 + g*8);
      bf16x8s kf2 = (g==0) ? *(const bf16x8s*)(krow + 64) : zf;
      #pragma unroll
      for (int s=0;s<2;s++){
        f32x4 sc = (f32x4){0.f,0.f,0.f,0.f};
        sc = __builtin_amdgcn_mfma_f32_16x16x32_bf16(kf0, qf[s][0], sc,0,0,0);
        sc = __builtin_amdgcn_mfma_f32_16x16x32_bf16(kf1, qf[s][1], sc,0,0,0);
        sc = __builtin_amdgcn_mfma_f32_16x16x32_bf16(kf2, qf[s][2], sc,0,0,0);
        float p0 = __expf(sc[0]), p1 = __expf(sc[1]);
        float p2 = __expf(sc[2]), p3 = __expf(sc[3]);
        lsum[s] += (p0+p1) + (p2+p3);
        u32 w0 = (u32)f2bf(p0) | ((u32)f2bf(p1) << 16);
        u32 w1 = (u32)f2bf(p2) | ((u32)f2bf(p3) << 16);
        char* pb = s ? pb1 : pb0;
        int kb = nf*32 + g*8;
        *(u32*)(pb + ( kb      ^ swz)) = w0;
        *(u32*)(pb + ((kb + 4) ^ swz)) = w1;
      }
    }
    asm volatile("" ::: "memory");
    bf16x8s pa[2][2];
    #pragma unroll
    for (int s=0;s<2;s++)
      #pragma unroll
      for (int w2=0;w2<2;w2++)
        pa[s][w2] = *(const bf16x8s*)((s?pb1:pb0) + ((w2*64 + g*16) ^ swz));

    #pragma unroll
    for (int c5=0;c5<5;c5++){
      #pragma unroll
      for (int w2=0;w2<2;w2++){
        bf16x8s vf = *(const bf16x8s*)((const char*)Vlds + (size_t)(c5*16+c)*144 + w2*64 + g*16);
        oacc[0][c5] = __builtin_amdgcn_mfma_f32_16x16x32_bf16(pa[0][w2], vf, oacc[0][c5],0,0,0);
        oacc[1][c5] = __builtin_amdgcn_mfma_f32_16x16x32_bf16(pa[1][w2], vf, oacc[1][c5],0,0,0);
      }
    }

    if (t < 15){
      __syncthreads();
      *(int4*)((char*)Vlds + ((tid    )>>3)*144 + ((tid    )&7)*16) = vr0;
      *(int4*)((char*)Vlds + ((256+tid)>>3)*144 + ((256+tid)&7)*16) = vr1;
      if (tid < 64) *(int4*)((char*)Vlds + ((512+tid)>>3)*144 + ((512+tid)&7)*16) = vr2;
    }
  }

  size_t obase = (size_t)b*1024*1152 + (size_t)h*72;
  #pragma unroll
  for (int s=0;s<2;s++){
    float ls = lsum[s];
    ls += __shfl_xor(ls, 16);
    ls += __shfl_xor(ls, 32);
    float linv[4];
    #pragma unroll
    for (int r=0;r<4;r++) linv[r] = 1.0f / __shfl(ls, 4*g + r);
    #pragma unroll
    for (int c5=0;c5<5;c5++){
      int d = c5*16 + c;
      if (d < 72){
        #pragma unroll
        for (int r=0;r<4;r++){
          int n = q0 + wv*32 + s*16 + 4*g + r;
          O[obase + (size_t)n*1152 + d] = f2bf(oacc[s][c5][r]*linv[r]);
        }
      }
    }
  }
}

extern "C" void kernel_launch(void* const* d_in, const int* in_sizes, int n_in,
                              void* d_out, int out_size, void* d_ws, size_t ws_size,
                              hipStream_t stream) {
  const float* x    = (const float*)d_in[0];
  const float* temb = (const float*)d_in[1];
  const float* cos_y= (const float*)d_in[2];
  const float* sin_y= (const float*)d_in[3];
  const float* cos_x= (const float*)d_in[4];
  const float* sin_x= (const float*)d_in[5];
  const float* Wqkv = (const float*)d_in[6];
  const float* bqkv = (const float*)d_in[7];
  const float* Wt   = (const float*)d_in[8];
  const float* bt   = (const float*)d_in[9];
  const float* Wp   = (const float*)d_in[10];
  const float* bp   = (const float*)d_in[11];
  const float* qn_w = (const float*)d_in[12];
  const float* kn_w = (const float*)d_in[13];
  const float* Wg   = (const float*)d_in[14];
  const float* bg   = (const float*)d_in[15];
  const float* Wu   = (const float*)d_in[16];
  const float* bu   = (const float*)d_in[17];
  const float* Wd   = (const float*)d_in[18];
  const float* bd   = (const float*)d_in[19];

  char* ws = (char*)d_ws;
  size_t off = 0;
  auto alloc = [&](size_t bytes)->void*{
    off = (off + 255) & ~(size_t)255;
    void* p = ws + off; off += bytes; return p;
  };

  u16*   wbuf  = (u16*)alloc((size_t)6144*1152*2);          // shared bf16 weight buffer (max: gate+up interleaved)
  float* tvec  = (float*)alloc((size_t)16*3456*4);
  u16*   xn_bf = (u16*)alloc((size_t)16384*1152*2);         // norm1 out -> o (attn out) -> xn2
  u16*   qt    = (u16*)alloc((size_t)262144*72*2);          // gbuf starts here later
  u16*   kt    = (u16*)alloc((size_t)262144*72*2);
  u16*   vt    = (u16*)alloc((size_t)256*72*1024*2);
  if (off > ws_size) return;   // diagnostic guard: clean fail instead of OOB crash

  u16*   o_bf   = xn_bf;
  u16*   xn2_bf = xn_bf;
  u16*   gbuf   = qt;          // 100.7 MB <= qt+kt+vt region (113.2 MB)
  float* x1     = (float*)d_out;

  // norm1 + temb branch
  rms_kernel<<<16384,256,0,stream>>>(x, xn_bf, 1152);
  temb_kernel<<<864,256,0,stream>>>(temb, Wt, bt, bqkv, tvec);

  // QKV GEMM (scatter epilogue -> qt/kt/vt); 64 m-tiles x 27 n-tiles; segw=9
  cvt_kernel<<<(3456*288+255)/256,256,0,stream>>>(Wqkv, wbuf, 3456*288);
  gemm_kernel<0><<<64*27,512,0,stream>>>(
      xn_bf, wbuf, 16384, 3456, 1152, 27, 9, nullptr, tvec, qt, kt, vt);

  // q/k RMS + RoPE in place (q pre-scaled by 1/sqrt(72))
  qkrope_kernel<<<65536,256,0,stream>>>(qt, kt, qn_w, kn_w, cos_y, sin_y, cos_x, sin_x);

  // attention -> o_bf
  attn_kernel<<<2048,256,0,stream>>>(qt, kt, vt, o_bf);

  // proj + residual -> x1 (= d_out, fp32); 128 m-tiles x 9 n-tiles = 1152 blocks; segw=9
  cvt_kernel<<<(1152*288+255)/256,256,0,stream>>>(Wp, wbuf, 1152*288);
  gemm_half<1><<<128*9,256,0,stream>>>(
      o_bf, wbuf, 16384, 1152, 1152, 9, 9, bp, x, x1);

  // norm2
  rms_kernel<<<16384,256,0,stream>>>(x1, xn2_bf, 1152);

  // gate+up fused, 2-chunk 256x256 kernel; 64 m x 24 n = 1536 blocks; segw=4
  cvt_gu_kernel<<<(6144*288+255)/256,256,0,stream>>>(Wg, Wu, wbuf);
  gemm_gu8<<<1536,512,0,stream>>>(
      xn2_bf, wbuf, 1152, 24, 4, bg, bu, gbuf);

  // down + residual -> d_out (reads x1 == d_out element-wise, race-free); 128 x 9 = 1152; segw=3
  cvt_kernel<<<(3072*288+255)/256,256,0,stream>>>(Wd, wbuf, 3072*288);
  gemm_half<4><<<128*9,256,0,stream>>>(
      gbuf, wbuf, 16384, 1152, 3072, 9, 3, bd, x1, (float*)d_out);
}